// Round 1
// baseline (1363.466 us; speedup 1.0000x reference)
//
#include <hip/hip_runtime.h>
#include <hip/hip_bf16.h>

#define NN 65536
#define DD 512
#define HH 512
#define NSTEP 4
#define NEG_INFF -100000000.0f

#define ABLOCKS 2048
#define NWAVE (ABLOCKS * 4)   // 8192 waves; 8 rows per wave

// ---------- helpers ----------
__device__ __forceinline__ float bflo(unsigned u) {
    union { unsigned i; float f; } v; v.i = u << 16; return v.f;
}
__device__ __forceinline__ float bfhi(unsigned u) {
    union { unsigned i; float f; } v; v.i = u & 0xffff0000u; return v.f;
}
__device__ __forceinline__ float fast_tanh(float x) {
    // tanh(x) = 1 - 2/(e^{2x}+1); rcp ~1ulp, fine for score path
    float e = __expf(2.0f * x);
    return 1.0f - 2.0f * __builtin_amdgcn_rcpf(e + 1.0f);
}

// ---------- GEMM: feat = attn_mem @ W, f32 compute, bf16 store ----------
// grid (512, 8): by<4 -> W0/C0 (attn), else W1/C1 (hop); 128x128 tile, BK=16
#define GBM 128
#define GBN 128
#define GBK 16
__global__ __launch_bounds__(256)
void gemm_feat(const float* __restrict__ A,
               const float* __restrict__ W0, const float* __restrict__ W1,
               __hip_bfloat16* __restrict__ C0, __hip_bfloat16* __restrict__ C1) {
    __shared__ float As[GBK][GBM + 4];
    __shared__ float Bs[GBK][GBN + 4];
    const int by = blockIdx.y;
    const float* Wp = (by < 4) ? W0 : W1;
    __hip_bfloat16* Cp = (by < 4) ? C0 : C1;
    const int bn = (by & 3) * GBN;
    const int bm = blockIdx.x * GBM;
    const int tid = threadIdx.x;
    const int tx = tid & 15, ty = tid >> 4;

    float acc[8][8];
#pragma unroll
    for (int i = 0; i < 8; ++i)
#pragma unroll
        for (int j = 0; j < 8; ++j) acc[i][j] = 0.f;

    for (int k0 = 0; k0 < DD; k0 += GBK) {
#pragma unroll
        for (int u = 0; u < 2; ++u) {           // A tile: 128 rows x 16 k
            int idx = tid + u * 256;            // 0..511 float4s
            int row = idx >> 2, kc = (idx & 3) << 2;
            float4 av = *(const float4*)&A[(size_t)(bm + row) * DD + k0 + kc];
            As[kc + 0][row] = av.x; As[kc + 1][row] = av.y;
            As[kc + 2][row] = av.z; As[kc + 3][row] = av.w;
        }
#pragma unroll
        for (int u = 0; u < 2; ++u) {           // W tile: 16 k x 128 cols
            int idx = tid + u * 256;
            int r = idx >> 5, c = (idx & 31) << 2;
            float4 wv = *(const float4*)&Wp[(size_t)(k0 + r) * HH + bn + c];
            *(float4*)&Bs[r][c] = wv;
        }
        __syncthreads();
#pragma unroll
        for (int kk = 0; kk < GBK; ++kk) {
            float a[8], b[8];
            *(float4*)&a[0] = *(const float4*)&As[kk][ty * 8];
            *(float4*)&a[4] = *(const float4*)&As[kk][ty * 8 + 4];
            *(float4*)&b[0] = *(const float4*)&Bs[kk][tx * 8];
            *(float4*)&b[4] = *(const float4*)&Bs[kk][tx * 8 + 4];
#pragma unroll
            for (int i = 0; i < 8; ++i)
#pragma unroll
                for (int j = 0; j < 8; ++j) acc[i][j] += a[i] * b[j];
        }
        __syncthreads();
    }
#pragma unroll
    for (int i = 0; i < 8; ++i) {
        int row = bm + ty * 8 + i;
        union { __hip_bfloat16 h[8]; uint4 u; } tmp;
#pragma unroll
        for (int j = 0; j < 8; ++j) tmp.h[j] = __float2bfloat16(acc[i][j]);
        *(uint4*)&Cp[(size_t)row * HH + bn + tx * 8] = tmp.u;
    }
}

// ---------- LSTM ----------
// wave-per-gate-row: 2048 rows; grid 512 x 256
__global__ __launch_bounds__(256)
void lstm_gates(const float* __restrict__ x, const float* __restrict__ h,
                const float* __restrict__ w_ih, const float* __restrict__ w_hh,
                const float* __restrict__ b_ih, const float* __restrict__ b_hh,
                float* __restrict__ gates) {
    const int wave = (blockIdx.x * 256 + threadIdx.x) >> 6;
    const int lane = threadIdx.x & 63;
    const float* wi = w_ih + (size_t)wave * DD;
    const float* wh = w_hh + (size_t)wave * HH;
    float s = 0.f;
#pragma unroll
    for (int t = 0; t < 8; ++t) {
        int k = lane + 64 * t;
        s += wi[k] * x[k] + wh[k] * h[k];
    }
#pragma unroll
    for (int off = 32; off; off >>= 1) s += __shfl_xor(s, off, 64);
    if (lane == 0) gates[wave] = s + b_ih[wave] + b_hh[wave];
}

__global__ void lstm_hc(const float* __restrict__ gates, const float* __restrict__ cin,
                        float* __restrict__ cout, float* __restrict__ hout) {
    const int j = threadIdx.x;   // 512
    float ig = gates[j], fg = gates[HH + j], gg = gates[2 * HH + j], og = gates[3 * HH + j];
    float si = 1.f / (1.f + expf(-ig));
    float sf = 1.f / (1.f + expf(-fg));
    float so = 1.f / (1.f + expf(-og));
    float cn = sf * cin[j] + si * tanhf(gg);
    cout[j] = cn;
    hout[j] = so * tanhf(cn);
}

// ---------- qw = q @ W (512x512), grid 8 x 512 ----------
__global__ __launch_bounds__(512)
void vecmat512(const float* __restrict__ q, const float* __restrict__ W,
               float* __restrict__ out) {
    __shared__ float red[8][64];
    const int lane = threadIdx.x & 63, wv = threadIdx.x >> 6;
    const int j = blockIdx.x * 64 + lane;
    float s = 0.f;
    const int k0 = wv * 64;
#pragma unroll 4
    for (int k = k0; k < k0 + 64; ++k) s += q[k] * W[(size_t)k * HH + j];
    red[wv][lane] = s;
    __syncthreads();
    if (wv == 0) {
        float t = 0.f;
#pragma unroll
        for (int r = 0; r < 8; ++r) t += red[r][lane];
        out[j] = t;
    }
}

// ---------- attention phase A: streaming online-softmax partials ----------
template<bool HOP>
__global__ __launch_bounds__(256)
void attn_partial(const __hip_bfloat16* __restrict__ feat,
                  const float* __restrict__ mem,      // only used when !HOP
                  const float* __restrict__ qw,
                  const float* __restrict__ v,
                  const int* __restrict__ mask,
                  float* __restrict__ pm, float* __restrict__ pl,
                  float* __restrict__ pacc) {
    const int gtid = blockIdx.x * 256 + threadIdx.x;
    const int wave = gtid >> 6;
    const int lane = threadIdx.x & 63;
    float qv[8], vv[8];
    {
        float4 q0 = *(const float4*)&qw[lane * 8];
        float4 q1 = *(const float4*)&qw[lane * 8 + 4];
        qv[0] = q0.x; qv[1] = q0.y; qv[2] = q0.z; qv[3] = q0.w;
        qv[4] = q1.x; qv[5] = q1.y; qv[6] = q1.z; qv[7] = q1.w;
        float4 v0 = *(const float4*)&v[lane * 8];
        float4 v1 = *(const float4*)&v[lane * 8 + 4];
        vv[0] = v0.x; vv[1] = v0.y; vv[2] = v0.z; vv[3] = v0.w;
        vv[4] = v1.x; vv[5] = v1.y; vv[6] = v1.z; vv[7] = v1.w;
    }
    float m = -3.0e38f, lsum = 0.f;
    float acc[8];
#pragma unroll
    for (int j = 0; j < 8; ++j) acc[j] = 0.f;
    const int row0 = wave * 8;
    for (int r = 0; r < 8; ++r) {
        const int i = row0 + r;
        const uint4 raw = *(const uint4*)(feat + (size_t)i * HH + lane * 8);
        float f[8];
        f[0] = bflo(raw.x); f[1] = bfhi(raw.x); f[2] = bflo(raw.y); f[3] = bfhi(raw.y);
        f[4] = bflo(raw.z); f[5] = bfhi(raw.z); f[6] = bflo(raw.w); f[7] = bfhi(raw.w);
        float mv[8];
        if (!HOP) {
            float4 m0 = *(const float4*)&mem[(size_t)i * DD + lane * 8];
            float4 m1 = *(const float4*)&mem[(size_t)i * DD + lane * 8 + 4];
            mv[0] = m0.x; mv[1] = m0.y; mv[2] = m0.z; mv[3] = m0.w;
            mv[4] = m1.x; mv[5] = m1.y; mv[6] = m1.z; mv[7] = m1.w;
        } else {
#pragma unroll
            for (int j = 0; j < 8; ++j) mv[j] = f[j];
        }
        float d = 0.f;
#pragma unroll
        for (int j = 0; j < 8; ++j) d += fast_tanh(f[j] + qv[j]) * vv[j];
#pragma unroll
        for (int off = 32; off; off >>= 1) d += __shfl_xor(d, off, 64);
        const float sc = d + (mask[i] ? 0.f : NEG_INFF);
        const float mn = fmaxf(m, sc);
        const float fac = __expf(m - mn);
        const float p = __expf(sc - mn);
        lsum = lsum * fac + p;
#pragma unroll
        for (int j = 0; j < 8; ++j) acc[j] = acc[j] * fac + p * mv[j];
        m = mn;
    }
    const size_t base = (size_t)wave * HH + lane * 8;
    *(float4*)&pacc[base]     = make_float4(acc[0], acc[1], acc[2], acc[3]);
    *(float4*)&pacc[base + 4] = make_float4(acc[4], acc[5], acc[6], acc[7]);
    if (lane == 0) { pm[wave] = m; pl[wave] = lsum; }
}

// ---------- attention phase B: combine partials -> out[512]; grid 64 x 256 ----------
__global__ __launch_bounds__(256)
void attn_combine(const float* __restrict__ pm, const float* __restrict__ pl,
                  const float* __restrict__ pacc, float* __restrict__ out) {
    __shared__ float wts[NWAVE];
    __shared__ float red[256];
    const int tid = threadIdx.x;
    const int lane = tid & 63, wv = tid >> 6;
    // global max
    float mx = -3.0e38f;
    for (int b = tid; b < NWAVE; b += 256) mx = fmaxf(mx, pm[b]);
#pragma unroll
    for (int off = 32; off; off >>= 1) mx = fmaxf(mx, __shfl_xor(mx, off, 64));
    if (lane == 0) red[wv] = mx;
    __syncthreads();
    const float mg = fmaxf(fmaxf(red[0], red[1]), fmaxf(red[2], red[3]));
    __syncthreads();
    // weights + global denom
    float lg = 0.f;
    for (int b = tid; b < NWAVE; b += 256) {
        float wq = __expf(pm[b] - mg);
        wts[b] = wq;
        lg += wq * pl[b];
    }
#pragma unroll
    for (int off = 32; off; off >>= 1) lg += __shfl_xor(lg, off, 64);
    if (lane == 0) red[wv] = lg;
    __syncthreads();
    lg = red[0] + red[1] + red[2] + red[3];
    const float inv = 1.0f / lg;
    __syncthreads();
    // 8 columns per block
    const int c0 = blockIdx.x * 8;
    float a[8];
#pragma unroll
    for (int j = 0; j < 8; ++j) a[j] = 0.f;
    for (int b = tid; b < NWAVE; b += 256) {
        float wq = wts[b];
        float4 p0 = *(const float4*)&pacc[(size_t)b * HH + c0];
        float4 p1 = *(const float4*)&pacc[(size_t)b * HH + c0 + 4];
        a[0] += wq * p0.x; a[1] += wq * p0.y; a[2] += wq * p0.z; a[3] += wq * p0.w;
        a[4] += wq * p1.x; a[5] += wq * p1.y; a[6] += wq * p1.z; a[7] += wq * p1.w;
    }
#pragma unroll
    for (int j = 0; j < 8; ++j)
#pragma unroll
        for (int off = 32; off; off >>= 1) a[j] += __shfl_xor(a[j], off, 64);
    if (lane == 0) {
#pragma unroll
        for (int j = 0; j < 8; ++j) red[wv * 8 + j] = a[j];
    }
    __syncthreads();
    if (tid < 8) {
        float s = red[tid] + red[8 + tid] + red[16 + tid] + red[24 + tid];
        out[c0 + tid] = s * inv;
    }
}

// ---------- score ----------
__global__ void score_k(const float* __restrict__ x, const float* __restrict__ sw,
                        const float* __restrict__ sb, float* __restrict__ out) {
    const int lane = threadIdx.x;   // 64
    float s = 0.f;
#pragma unroll
    for (int t = 0; t < 8; ++t) {
        int k = lane + 64 * t;
        s += x[k] * sw[k];
    }
#pragma unroll
    for (int off = 32; off; off >>= 1) s += __shfl_xor(s, off, 64);
    if (lane == 0) out[0] = s + sb[0];
}

// ---------- launcher ----------
extern "C" void kernel_launch(void* const* d_in, const int* in_sizes, int n_in,
                              void* d_out, int out_size, void* d_ws, size_t ws_size,
                              hipStream_t stream) {
    (void)in_sizes; (void)n_in; (void)out_size; (void)ws_size;
    const float* attn_mem = (const float*)d_in[0];
    const float* attn_wm  = (const float*)d_in[1];
    const float* attn_wq  = (const float*)d_in[2];
    const float* attn_v   = (const float*)d_in[3];
    const float* hop_wm   = (const float*)d_in[4];
    const float* hop_wq   = (const float*)d_in[5];
    const float* hop_v    = (const float*)d_in[6];
    const float* init_i   = (const float*)d_in[7];
    const float* init_h   = (const float*)d_in[8];
    const float* init_c   = (const float*)d_in[9];
    const float* w_ih     = (const float*)d_in[10];
    const float* w_hh     = (const float*)d_in[11];
    const float* b_ih     = (const float*)d_in[12];
    const float* b_hh     = (const float*)d_in[13];
    const float* score_w  = (const float*)d_in[14];
    const float* score_b  = (const float*)d_in[15];
    const int*   mask     = (const int*)d_in[16];
    float* dout = (float*)d_out;

    // workspace carve (256B aligned)
    size_t off = 0;
    char* base = (char*)d_ws;
    auto carve = [&](size_t bytes) -> char* {
        char* p = base + off;
        off += (bytes + 255) & ~(size_t)255;
        return p;
    };
    __hip_bfloat16* afeat = (__hip_bfloat16*)carve((size_t)NN * HH * 2);
    __hip_bfloat16* hfeat = (__hip_bfloat16*)carve((size_t)NN * HH * 2);
    float* pacc  = (float*)carve((size_t)NWAVE * HH * 4);
    float* pm    = (float*)carve((size_t)NWAVE * 4);
    float* pl    = (float*)carve((size_t)NWAVE * 4);
    float* gates = (float*)carve(4 * HH * 4);
    float* hbuf  = (float*)carve(HH * 4);
    float* cbuf  = (float*)carve(HH * 4);
    float* qbuf  = (float*)carve(HH * 4);
    float* qwbuf = (float*)carve(HH * 4);
    float* xbuf  = (float*)carve(DD * 4);

    // precompute features (both GEMMs in one launch)
    gemm_feat<<<dim3(NN / GBM, 8), 256, 0, stream>>>(attn_mem, attn_wm, hop_wm, afeat, hfeat);

    for (int s = 0; s < NSTEP; ++s) {
        const float* x   = s ? xbuf : init_i;
        const float* hin = s ? hbuf : init_h;
        const float* cin = s ? cbuf : init_c;
        lstm_gates<<<512, 256, 0, stream>>>(x, hin, w_ih, w_hh, b_ih, b_hh, gates);
        lstm_hc<<<1, 512, 0, stream>>>(gates, cin, cbuf, hbuf);
        // hop attention: query = h
        vecmat512<<<8, 512, 0, stream>>>(hbuf, hop_wq, qwbuf);
        attn_partial<true><<<ABLOCKS, 256, 0, stream>>>(hfeat, nullptr, qwbuf, hop_v, mask, pm, pl, pacc);
        attn_combine<<<64, 256, 0, stream>>>(pm, pl, pacc, qbuf);
        // final attention: query = hop out
        vecmat512<<<8, 512, 0, stream>>>(qbuf, attn_wq, qwbuf);
        attn_partial<false><<<ABLOCKS, 256, 0, stream>>>(afeat, attn_mem, qwbuf, attn_v, mask, pm, pl, pacc);
        attn_combine<<<64, 256, 0, stream>>>(pm, pl, pacc, xbuf);
        score_k<<<1, 64, 0, stream>>>(xbuf, score_w, score_b, dout + s);
    }
}

// Round 2
// 669.038 us; speedup vs baseline: 2.0379x; 2.0379x over previous
//
#include <hip/hip_runtime.h>
#include <hip/hip_bf16.h>

#define NN 65536
#define DD 512
#define HH 512
#define NSTEP 4
#define NEG_INFF -100000000.0f

#define ABLOCKS 2048
#define NWAVE (ABLOCKS * 4)   // 8192 waves; 8 rows per wave

typedef unsigned short ushort_t;
typedef __attribute__((ext_vector_type(8))) short bf16x8;
typedef __attribute__((ext_vector_type(4))) float f32x4;

// ---------- helpers ----------
__device__ __forceinline__ float bflo(unsigned u) {
    union { unsigned i; float f; } v; v.i = u << 16; return v.f;
}
__device__ __forceinline__ float bfhi(unsigned u) {
    union { unsigned i; float f; } v; v.i = u & 0xffff0000u; return v.f;
}
__device__ __forceinline__ float fast_tanh(float x) {
    float e = __expf(2.0f * x);
    return 1.0f - 2.0f * __builtin_amdgcn_rcpf(e + 1.0f);
}

#define GL2LDS(g, l) __builtin_amdgcn_global_load_lds( \
    (const __attribute__((address_space(1))) unsigned int*)(g), \
    (__attribute__((address_space(3))) unsigned int*)(l), 16, 0, 0)

// ---------- f32 -> bf16 convert (attn_mem), 8 elems/thread ----------
__global__ __launch_bounds__(256)
void conv_bf16(const float* __restrict__ in, ushort_t* __restrict__ out) {
    const int i = blockIdx.x * 256 + threadIdx.x;   // 8 floats per thread
    const size_t base = (size_t)i * 8;
    float4 a = *(const float4*)&in[base];
    float4 b = *(const float4*)&in[base + 4];
    union { __hip_bfloat16 h[8]; uint4 u; } t;
    t.h[0] = __float2bfloat16(a.x); t.h[1] = __float2bfloat16(a.y);
    t.h[2] = __float2bfloat16(a.z); t.h[3] = __float2bfloat16(a.w);
    t.h[4] = __float2bfloat16(b.x); t.h[5] = __float2bfloat16(b.y);
    t.h[6] = __float2bfloat16(b.z); t.h[7] = __float2bfloat16(b.w);
    *(uint4*)&out[base] = t.u;
}

// ---------- weight transpose + convert: WT[n][k] = bf16(W[k][n]) ----------
// grid (128, 2): 4 WT rows per block
__global__ __launch_bounds__(256)
void conv_wt(const float* __restrict__ W0, const float* __restrict__ W1,
             ushort_t* __restrict__ T0, ushort_t* __restrict__ T1) {
    const float* W = blockIdx.y ? W1 : W0;
    ushort_t* T = blockIdx.y ? T1 : T0;
    const int n = blockIdx.x * 4 + (threadIdx.x >> 6);
    const int k0 = (threadIdx.x & 63) * 8;
    union { __hip_bfloat16 h[8]; uint4 u; } t;
#pragma unroll
    for (int i = 0; i < 8; ++i)
        t.h[i] = __float2bfloat16(W[(size_t)(k0 + i) * HH + n]);
    *(uint4*)&T[(size_t)n * DD + k0] = t.u;
}

// ---------- MFMA GEMM: C = A(bf16) @ WT^T(bf16) -> bf16 ----------
// grid (512, 8): y<4 -> attn (WT0,C0) else hop (WT1,C1); 128x128 tile, BK=32
#define TM 128
#define TK 32
__global__ __launch_bounds__(256)
void gemm_mfma(const ushort_t* __restrict__ A,
               const ushort_t* __restrict__ WT0, const ushort_t* __restrict__ WT1,
               __hip_bfloat16* __restrict__ C0, __hip_bfloat16* __restrict__ C1) {
    __shared__ ushort_t As[TM * TK];   // [128 rows][32 k], linear
    __shared__ ushort_t Bs[TM * TK];   // [128 cols][32 k], linear
    const int my = blockIdx.y;
    const ushort_t* WT = (my < 4) ? WT0 : WT1;
    __hip_bfloat16* Cp = (my < 4) ? C0 : C1;
    const int bn = (my & 3) * TM;
    const int bm = blockIdx.x * TM;
    const int tid = threadIdx.x;
    const int lane = tid & 63;
    const int wid = tid >> 6;
    const int wr = (wid >> 1) * 64;    // wave's output rows
    const int wc = (wid & 1) * 64;     // wave's output cols
    const int l15 = lane & 15;
    const int kf = (lane >> 4) * 8;    // fragment k offset
    const int srow = lane >> 2;        // staging: row within 16-row chunk
    const int ske = (lane & 3) * 8;    // staging: k elem offset

    const f32x4 zero = {0.f, 0.f, 0.f, 0.f};
    f32x4 acc[4][4];
#pragma unroll
    for (int m = 0; m < 4; ++m)
#pragma unroll
        for (int n = 0; n < 4; ++n) acc[m][n] = zero;

    for (int k0 = 0; k0 < DD; k0 += TK) {
        __syncthreads();
#pragma unroll
        for (int u = 0; u < 2; ++u) {
            const int chunk = u * 4 + wid;              // 0..7 (16 rows each)
            const int row = chunk * 16 + srow;
            GL2LDS(A + (size_t)(bm + row) * DD + k0 + ske, As + chunk * 512);
            GL2LDS(WT + (size_t)(bn + row) * DD + k0 + ske, Bs + chunk * 512);
        }
        __syncthreads();
        bf16x8 af[4], bfr[4];
#pragma unroll
        for (int m = 0; m < 4; ++m)
            af[m] = *(const bf16x8*)(As + (wr + m * 16 + l15) * TK + kf);
#pragma unroll
        for (int n = 0; n < 4; ++n)
            bfr[n] = *(const bf16x8*)(Bs + (wc + n * 16 + l15) * TK + kf);
#pragma unroll
        for (int m = 0; m < 4; ++m)
#pragma unroll
            for (int n = 0; n < 4; ++n)
                acc[m][n] = __builtin_amdgcn_mfma_f32_16x16x32_bf16(af[m], bfr[n], acc[m][n], 0, 0, 0);
    }
    // epilogue: D[row=(lane>>4)*4+r][col=lane&15]
    const int r0 = (lane >> 4) * 4;
#pragma unroll
    for (int m = 0; m < 4; ++m) {
#pragma unroll
        for (int n = 0; n < 4; ++n) {
            const f32x4 v = acc[m][n];
            const size_t base = (size_t)(bm + wr + m * 16 + r0) * HH + bn + wc + n * 16 + l15;
#pragma unroll
            for (int r = 0; r < 4; ++r)
                Cp[base + (size_t)r * HH] = __float2bfloat16(v[r]);
        }
    }
}

// ---------- LSTM ----------
__global__ __launch_bounds__(256)
void lstm_gates(const float* __restrict__ x, const float* __restrict__ h,
                const float* __restrict__ w_ih, const float* __restrict__ w_hh,
                const float* __restrict__ b_ih, const float* __restrict__ b_hh,
                float* __restrict__ gates) {
    const int wave = (blockIdx.x * 256 + threadIdx.x) >> 6;
    const int lane = threadIdx.x & 63;
    const float* wi = w_ih + (size_t)wave * DD;
    const float* wh = w_hh + (size_t)wave * HH;
    float s = 0.f;
#pragma unroll
    for (int t = 0; t < 8; ++t) {
        int k = lane + 64 * t;
        s += wi[k] * x[k] + wh[k] * h[k];
    }
#pragma unroll
    for (int off = 32; off; off >>= 1) s += __shfl_xor(s, off, 64);
    if (lane == 0) gates[wave] = s + b_ih[wave] + b_hh[wave];
}

__global__ void lstm_hc(const float* __restrict__ gates, const float* __restrict__ cin,
                        float* __restrict__ cout, float* __restrict__ hout) {
    const int j = threadIdx.x;   // 512
    float ig = gates[j], fg = gates[HH + j], gg = gates[2 * HH + j], og = gates[3 * HH + j];
    float si = 1.f / (1.f + expf(-ig));
    float sf = 1.f / (1.f + expf(-fg));
    float so = 1.f / (1.f + expf(-og));
    float cn = sf * cin[j] + si * tanhf(gg);
    cout[j] = cn;
    hout[j] = so * tanhf(cn);
}

// ---------- qw = q @ W (512x512), grid 8 x 512 ----------
__global__ __launch_bounds__(512)
void vecmat512(const float* __restrict__ q, const float* __restrict__ W,
               float* __restrict__ out) {
    __shared__ float red[8][64];
    const int lane = threadIdx.x & 63, wv = threadIdx.x >> 6;
    const int j = blockIdx.x * 64 + lane;
    float s = 0.f;
    const int k0 = wv * 64;
#pragma unroll 4
    for (int k = k0; k < k0 + 64; ++k) s += q[k] * W[(size_t)k * HH + j];
    red[wv][lane] = s;
    __syncthreads();
    if (wv == 0) {
        float t = 0.f;
#pragma unroll
        for (int r = 0; r < 8; ++r) t += red[r][lane];
        out[j] = t;
    }
}

// ---------- attention phase A: streaming online-softmax partials ----------
template<bool HOP>
__global__ __launch_bounds__(256)
void attn_partial(const ushort_t* __restrict__ feat,
                  const ushort_t* __restrict__ mem,     // bf16 values (unused when HOP)
                  const float* __restrict__ qw,
                  const float* __restrict__ v,
                  const int* __restrict__ mask,
                  float* __restrict__ pm, float* __restrict__ pl,
                  float* __restrict__ pacc) {
    const int gtid = blockIdx.x * 256 + threadIdx.x;
    const int wave = gtid >> 6;
    const int lane = threadIdx.x & 63;
    float qv[8], vv[8];
    {
        float4 q0 = *(const float4*)&qw[lane * 8];
        float4 q1 = *(const float4*)&qw[lane * 8 + 4];
        qv[0] = q0.x; qv[1] = q0.y; qv[2] = q0.z; qv[3] = q0.w;
        qv[4] = q1.x; qv[5] = q1.y; qv[6] = q1.z; qv[7] = q1.w;
        float4 v0 = *(const float4*)&v[lane * 8];
        float4 v1 = *(const float4*)&v[lane * 8 + 4];
        vv[0] = v0.x; vv[1] = v0.y; vv[2] = v0.z; vv[3] = v0.w;
        vv[4] = v1.x; vv[5] = v1.y; vv[6] = v1.z; vv[7] = v1.w;
    }
    float m = -3.0e38f, lsum = 0.f;
    float acc[8];
#pragma unroll
    for (int j = 0; j < 8; ++j) acc[j] = 0.f;
    const int row0 = wave * 8;
    for (int r = 0; r < 8; ++r) {
        const int i = row0 + r;
        const uint4 raw = *(const uint4*)(feat + (size_t)i * HH + lane * 8);
        float f[8];
        f[0] = bflo(raw.x); f[1] = bfhi(raw.x); f[2] = bflo(raw.y); f[3] = bfhi(raw.y);
        f[4] = bflo(raw.z); f[5] = bfhi(raw.z); f[6] = bflo(raw.w); f[7] = bfhi(raw.w);
        float mv[8];
        if (!HOP) {
            const uint4 mraw = *(const uint4*)(mem + (size_t)i * DD + lane * 8);
            mv[0] = bflo(mraw.x); mv[1] = bfhi(mraw.x); mv[2] = bflo(mraw.y); mv[3] = bfhi(mraw.y);
            mv[4] = bflo(mraw.z); mv[5] = bfhi(mraw.z); mv[6] = bflo(mraw.w); mv[7] = bfhi(mraw.w);
        } else {
#pragma unroll
            for (int j = 0; j < 8; ++j) mv[j] = f[j];
        }
        float d = 0.f;
#pragma unroll
        for (int j = 0; j < 8; ++j) d += fast_tanh(f[j] + qv[j]) * vv[j];
#pragma unroll
        for (int off = 32; off; off >>= 1) d += __shfl_xor(d, off, 64);
        const float sc = d + (mask[i] ? 0.f : NEG_INFF);
        const float mn = fmaxf(m, sc);
        const float fac = __expf(m - mn);
        const float p = __expf(sc - mn);
        lsum = lsum * fac + p;
#pragma unroll
        for (int j = 0; j < 8; ++j) acc[j] = acc[j] * fac + p * mv[j];
        m = mn;
    }
    const size_t base = (size_t)wave * HH + lane * 8;
    *(float4*)&pacc[base]     = make_float4(acc[0], acc[1], acc[2], acc[3]);
    *(float4*)&pacc[base + 4] = make_float4(acc[4], acc[5], acc[6], acc[7]);
    if (lane == 0) { pm[wave] = m; pl[wave] = lsum; }
}

// ---------- attention phase B: combine partials -> out[512]; grid 64 x 256 ----------
__global__ __launch_bounds__(256)
void attn_combine(const float* __restrict__ pm, const float* __restrict__ pl,
                  const float* __restrict__ pacc, float* __restrict__ out) {
    __shared__ float wts[NWAVE];
    __shared__ float red[256];
    const int tid = threadIdx.x;
    const int lane = tid & 63, wv = tid >> 6;
    float mx = -3.0e38f;
    for (int b = tid; b < NWAVE; b += 256) mx = fmaxf(mx, pm[b]);
#pragma unroll
    for (int off = 32; off; off >>= 1) mx = fmaxf(mx, __shfl_xor(mx, off, 64));
    if (lane == 0) red[wv] = mx;
    __syncthreads();
    const float mg = fmaxf(fmaxf(red[0], red[1]), fmaxf(red[2], red[3]));
    __syncthreads();
    float lg = 0.f;
    for (int b = tid; b < NWAVE; b += 256) {
        float wq = __expf(pm[b] - mg);
        wts[b] = wq;
        lg += wq * pl[b];
    }
#pragma unroll
    for (int off = 32; off; off >>= 1) lg += __shfl_xor(lg, off, 64);
    if (lane == 0) red[wv] = lg;
    __syncthreads();
    lg = red[0] + red[1] + red[2] + red[3];
    const float inv = 1.0f / lg;
    __syncthreads();
    const int c0 = blockIdx.x * 8;
    float a[8];
#pragma unroll
    for (int j = 0; j < 8; ++j) a[j] = 0.f;
    for (int b = tid; b < NWAVE; b += 256) {
        float wq = wts[b];
        float4 p0 = *(const float4*)&pacc[(size_t)b * HH + c0];
        float4 p1 = *(const float4*)&pacc[(size_t)b * HH + c0 + 4];
        a[0] += wq * p0.x; a[1] += wq * p0.y; a[2] += wq * p0.z; a[3] += wq * p0.w;
        a[4] += wq * p1.x; a[5] += wq * p1.y; a[6] += wq * p1.z; a[7] += wq * p1.w;
    }
#pragma unroll
    for (int j = 0; j < 8; ++j)
#pragma unroll
        for (int off = 32; off; off >>= 1) a[j] += __shfl_xor(a[j], off, 64);
    if (lane == 0) {
#pragma unroll
        for (int j = 0; j < 8; ++j) red[wv * 8 + j] = a[j];
    }
    __syncthreads();
    if (tid < 8) {
        float s = red[tid] + red[8 + tid] + red[16 + tid] + red[24 + tid];
        out[c0 + tid] = s * inv;
    }
}

// ---------- score ----------
__global__ void score_k(const float* __restrict__ x, const float* __restrict__ sw,
                        const float* __restrict__ sb, float* __restrict__ out) {
    const int lane = threadIdx.x;   // 64
    float s = 0.f;
#pragma unroll
    for (int t = 0; t < 8; ++t) {
        int k = lane + 64 * t;
        s += x[k] * sw[k];
    }
#pragma unroll
    for (int off = 32; off; off >>= 1) s += __shfl_xor(s, off, 64);
    if (lane == 0) out[0] = s + sb[0];
}

// ---------- launcher ----------
extern "C" void kernel_launch(void* const* d_in, const int* in_sizes, int n_in,
                              void* d_out, int out_size, void* d_ws, size_t ws_size,
                              hipStream_t stream) {
    (void)in_sizes; (void)n_in; (void)out_size; (void)ws_size;
    const float* attn_mem = (const float*)d_in[0];
    const float* attn_wm  = (const float*)d_in[1];
    const float* attn_wq  = (const float*)d_in[2];
    const float* attn_v   = (const float*)d_in[3];
    const float* hop_wm   = (const float*)d_in[4];
    const float* hop_wq   = (const float*)d_in[5];
    const float* hop_v    = (const float*)d_in[6];
    const float* init_i   = (const float*)d_in[7];
    const float* init_h   = (const float*)d_in[8];
    const float* init_c   = (const float*)d_in[9];
    const float* w_ih     = (const float*)d_in[10];
    const float* w_hh     = (const float*)d_in[11];
    const float* b_ih     = (const float*)d_in[12];
    const float* b_hh     = (const float*)d_in[13];
    const float* score_w  = (const float*)d_in[14];
    const float* score_b  = (const float*)d_in[15];
    const int*   mask     = (const int*)d_in[16];
    float* dout = (float*)d_out;

    size_t off = 0;
    char* base = (char*)d_ws;
    auto carve = [&](size_t bytes) -> char* {
        char* p = base + off;
        off += (bytes + 255) & ~(size_t)255;
        return p;
    };
    ushort_t* Abf  = (ushort_t*)carve((size_t)NN * DD * 2);
    ushort_t* WT0  = (ushort_t*)carve((size_t)DD * HH * 2);
    ushort_t* WT1  = (ushort_t*)carve((size_t)DD * HH * 2);
    ushort_t* afeat = (ushort_t*)carve((size_t)NN * HH * 2);
    ushort_t* hfeat = (ushort_t*)carve((size_t)NN * HH * 2);
    float* pacc  = (float*)carve((size_t)NWAVE * HH * 4);
    float* pm    = (float*)carve((size_t)NWAVE * 4);
    float* pl    = (float*)carve((size_t)NWAVE * 4);
    float* gates = (float*)carve(4 * HH * 4);
    float* hbuf  = (float*)carve(HH * 4);
    float* cbuf  = (float*)carve(HH * 4);
    float* qbuf  = (float*)carve(HH * 4);
    float* qwbuf = (float*)carve(HH * 4);
    float* xbuf  = (float*)carve(DD * 4);

    // precompute: bf16 memory, transposed bf16 weights, features via MFMA
    conv_bf16<<<(NN * DD / 8) / 256, 256, 0, stream>>>(attn_mem, Abf);
    conv_wt<<<dim3(128, 2), 256, 0, stream>>>(attn_wm, hop_wm, WT0, WT1);
    gemm_mfma<<<dim3(NN / TM, 8), 256, 0, stream>>>(Abf, WT0, WT1,
        (__hip_bfloat16*)afeat, (__hip_bfloat16*)hfeat);

    for (int s = 0; s < NSTEP; ++s) {
        const float* x   = s ? xbuf : init_i;
        const float* hin = s ? hbuf : init_h;
        const float* cin = s ? cbuf : init_c;
        lstm_gates<<<512, 256, 0, stream>>>(x, hin, w_ih, w_hh, b_ih, b_hh, gates);
        lstm_hc<<<1, 512, 0, stream>>>(gates, cin, cbuf, hbuf);
        // hop attention: query = h; values = hop features
        vecmat512<<<8, 512, 0, stream>>>(hbuf, hop_wq, qwbuf);
        attn_partial<true><<<ABLOCKS, 256, 0, stream>>>(hfeat, nullptr, qwbuf, hop_v, mask, pm, pl, pacc);
        attn_combine<<<64, 256, 0, stream>>>(pm, pl, pacc, qbuf);
        // final attention: query = hop out; values = bf16 attn_mem
        vecmat512<<<8, 512, 0, stream>>>(qbuf, attn_wq, qwbuf);
        attn_partial<false><<<ABLOCKS, 256, 0, stream>>>(afeat, Abf, qwbuf, attn_v, mask, pm, pl, pacc);
        attn_combine<<<64, 256, 0, stream>>>(pm, pl, pacc, xbuf);
        score_k<<<1, 64, 0, stream>>>(xbuf, score_w, score_b, dout + s);
    }
}

// Round 3
// 515.552 us; speedup vs baseline: 2.6447x; 1.2977x over previous
//
#include <hip/hip_runtime.h>
#include <hip/hip_bf16.h>

#define NN 65536
#define DD 512
#define HH 512
#define NSTEP 4
#define NEG_INFF -100000000.0f

#define RPW 16                 // rows per wave in attn_partial
#define ABLOCKS 1024
#define NWAVE (ABLOCKS * 4)    // 4096 waves x 16 rows = 65536

typedef unsigned short ushort_t;
typedef __attribute__((ext_vector_type(8))) short bf16x8;
typedef __attribute__((ext_vector_type(4))) float f32x4;

// ---------- helpers ----------
__device__ __forceinline__ float bflo(unsigned u) {
    union { unsigned i; float f; } v; v.i = u << 16; return v.f;
}
__device__ __forceinline__ float bfhi(unsigned u) {
    union { unsigned i; float f; } v; v.i = u & 0xffff0000u; return v.f;
}
__device__ __forceinline__ float fast_tanh(float x) {
    float e = __expf(2.0f * x);
    return 1.0f - 2.0f * __builtin_amdgcn_rcpf(e + 1.0f);
}

#define GL2LDS(g, l) __builtin_amdgcn_global_load_lds( \
    (const __attribute__((address_space(1))) unsigned int*)(g), \
    (__attribute__((address_space(3))) unsigned int*)(l), 16, 0, 0)

// ---------- f32 -> bf16 convert (attn_mem) ----------
__global__ __launch_bounds__(256)
void conv_bf16(const float* __restrict__ in, ushort_t* __restrict__ out) {
    const int i = blockIdx.x * 256 + threadIdx.x;
    const size_t base = (size_t)i * 8;
    float4 a = *(const float4*)&in[base];
    float4 b = *(const float4*)&in[base + 4];
    union { __hip_bfloat16 h[8]; uint4 u; } t;
    t.h[0] = __float2bfloat16(a.x); t.h[1] = __float2bfloat16(a.y);
    t.h[2] = __float2bfloat16(a.z); t.h[3] = __float2bfloat16(a.w);
    t.h[4] = __float2bfloat16(b.x); t.h[5] = __float2bfloat16(b.y);
    t.h[6] = __float2bfloat16(b.z); t.h[7] = __float2bfloat16(b.w);
    *(uint4*)&out[base] = t.u;
}

// ---------- weight transpose + convert: WT[n][k] = bf16(W[k][n]) ----------
__global__ __launch_bounds__(256)
void conv_wt(const float* __restrict__ W0, const float* __restrict__ W1,
             ushort_t* __restrict__ T0, ushort_t* __restrict__ T1) {
    const float* W = blockIdx.y ? W1 : W0;
    ushort_t* T = blockIdx.y ? T1 : T0;
    const int n = blockIdx.x * 4 + (threadIdx.x >> 6);
    const int k0 = (threadIdx.x & 63) * 8;
    union { __hip_bfloat16 h[8]; uint4 u; } t;
#pragma unroll
    for (int i = 0; i < 8; ++i)
        t.h[i] = __float2bfloat16(W[(size_t)(k0 + i) * HH + n]);
    *(uint4*)&T[(size_t)n * DD + k0] = t.u;
}

// ---------- MFMA GEMM with LDS XOR swizzle ----------
// grid (512, 8): y<4 -> attn else hop; 128x128 tile, BK=32
#define TM 128
#define TK 32
__global__ __launch_bounds__(256)
void gemm_mfma(const ushort_t* __restrict__ A,
               const ushort_t* __restrict__ WT0, const ushort_t* __restrict__ WT1,
               __hip_bfloat16* __restrict__ C0, __hip_bfloat16* __restrict__ C1) {
    __shared__ ushort_t As[TM * TK];   // [128 rows][32 k], chunk-swizzled
    __shared__ ushort_t Bs[TM * TK];
    const int my = blockIdx.y;
    const ushort_t* WT = (my < 4) ? WT0 : WT1;
    __hip_bfloat16* Cp = (my < 4) ? C0 : C1;
    const int bn = (my & 3) * TM;
    const int bm = blockIdx.x * TM;
    const int tid = threadIdx.x;
    const int lane = tid & 63;
    const int wid = tid >> 6;
    const int wr = (wid >> 1) * 64;
    const int wc = (wid & 1) * 64;
    const int l15 = lane & 15;
    // staging: lane holds physical chunk (lane&3) of row (lane>>2); source the
    // swizzled logical chunk so ds_read-side XOR lands on the right data.
    const int srow = lane >> 2;
    const int ske = (((lane & 3) ^ ((lane >> 3) & 3)) * 8);
    // read-side swizzled k offset (elements): chunk (lane>>4) XOR ((row>>1)&3)
    const int koff = (((lane >> 4) ^ ((l15 >> 1) & 3)) << 3);

    const f32x4 zero = {0.f, 0.f, 0.f, 0.f};
    f32x4 acc[4][4];
#pragma unroll
    for (int m = 0; m < 4; ++m)
#pragma unroll
        for (int n = 0; n < 4; ++n) acc[m][n] = zero;

    for (int k0 = 0; k0 < DD; k0 += TK) {
        __syncthreads();
#pragma unroll
        for (int u = 0; u < 2; ++u) {
            const int g = u * 4 + wid;                 // 16-row group 0..7
            const int row = g * 16 + srow;
            GL2LDS(A + (size_t)(bm + row) * DD + k0 + ske, As + g * 512);
            GL2LDS(WT + (size_t)(bn + row) * DD + k0 + ske, Bs + g * 512);
        }
        __syncthreads();
        bf16x8 af[4], bfr[4];
#pragma unroll
        for (int m = 0; m < 4; ++m)
            af[m] = *(const bf16x8*)(As + (wr + m * 16 + l15) * TK + koff);
#pragma unroll
        for (int n = 0; n < 4; ++n)
            bfr[n] = *(const bf16x8*)(Bs + (wc + n * 16 + l15) * TK + koff);
#pragma unroll
        for (int m = 0; m < 4; ++m)
#pragma unroll
            for (int n = 0; n < 4; ++n)
                acc[m][n] = __builtin_amdgcn_mfma_f32_16x16x32_bf16(af[m], bfr[n], acc[m][n], 0, 0, 0);
    }
    const int r0 = (lane >> 4) * 4;
#pragma unroll
    for (int m = 0; m < 4; ++m) {
#pragma unroll
        for (int n = 0; n < 4; ++n) {
            const f32x4 vv = acc[m][n];
            const size_t base = (size_t)(bm + wr + m * 16 + r0) * HH + bn + wc + n * 16 + l15;
#pragma unroll
            for (int r = 0; r < 4; ++r)
                Cp[base + (size_t)r * HH] = __float2bfloat16(vv[r]);
        }
    }
}

// ---------- LSTM gates ----------
__global__ __launch_bounds__(256)
void lstm_gates(const float* __restrict__ x, const float* __restrict__ h,
                const float* __restrict__ w_ih, const float* __restrict__ w_hh,
                const float* __restrict__ b_ih, const float* __restrict__ b_hh,
                float* __restrict__ gates) {
    const int wave = (blockIdx.x * 256 + threadIdx.x) >> 6;
    const int lane = threadIdx.x & 63;
    const float* wi = w_ih + (size_t)wave * DD;
    const float* wh = w_hh + (size_t)wave * HH;
    float s = 0.f;
#pragma unroll
    for (int t = 0; t < 8; ++t) {
        int k = lane + 64 * t;
        s += wi[k] * x[k] + wh[k] * h[k];
    }
#pragma unroll
    for (int off = 32; off; off >>= 1) s += __shfl_xor(s, off, 64);
    if (lane == 0) gates[wave] = s + b_ih[wave] + b_hh[wave];
}

// ---------- fused LSTM h/c + qw = h @ hop_wq ----------
// grid 8 x 512; every block redundantly computes h,c; block 0 persists them.
__global__ __launch_bounds__(512)
void lstm_tail(const float* __restrict__ gates, const float* __restrict__ cin,
               float* __restrict__ cout, float* __restrict__ hout,
               const float* __restrict__ Wq, float* __restrict__ qwout) {
    __shared__ float hs[HH];
    __shared__ float red[8][64];
    const int j = threadIdx.x;   // 512
    {
        float ig = gates[j], fg = gates[HH + j], gg = gates[2 * HH + j], og = gates[3 * HH + j];
        float si = 1.f / (1.f + __expf(-ig));
        float sf = 1.f / (1.f + __expf(-fg));
        float so = 1.f / (1.f + __expf(-og));
        float cn = sf * cin[j] + si * tanhf(gg);
        float hn = so * tanhf(cn);
        hs[j] = hn;
        if (blockIdx.x == 0) { cout[j] = cn; hout[j] = hn; }
    }
    __syncthreads();
    const int lane = threadIdx.x & 63, wv = threadIdx.x >> 6;
    const int col = blockIdx.x * 64 + lane;
    float s = 0.f;
    const int k0 = wv * 64;
#pragma unroll 4
    for (int k = k0; k < k0 + 64; ++k) s += hs[k] * Wq[(size_t)k * HH + col];
    red[wv][lane] = s;
    __syncthreads();
    if (wv == 0) {
        float t = 0.f;
#pragma unroll
        for (int r = 0; r < 8; ++r) t += red[r][lane];
        qwout[col] = t;
    }
}

// ---------- qw = q @ W (512x512), grid 8 x 512 ----------
__global__ __launch_bounds__(512)
void vecmat512(const float* __restrict__ q, const float* __restrict__ W,
               float* __restrict__ out) {
    __shared__ float red[8][64];
    const int lane = threadIdx.x & 63, wv = threadIdx.x >> 6;
    const int j = blockIdx.x * 64 + lane;
    float s = 0.f;
    const int k0 = wv * 64;
#pragma unroll 4
    for (int k = k0; k < k0 + 64; ++k) s += q[k] * W[(size_t)k * HH + j];
    red[wv][lane] = s;
    __syncthreads();
    if (wv == 0) {
        float t = 0.f;
#pragma unroll
        for (int r = 0; r < 8; ++r) t += red[r][lane];
        out[j] = t;
    }
}

// ---------- attention phase A: fixed-offset exp partials ----------
// softmax(sc) = exp(sc-C)/sum exp(sc-C) with C = sum|v| >= max sc (tanh in [-1,1])
// -> no online max, no cross-row serial chain. Masked rows: exp(-1e8) == 0.
template<bool HOP>
__global__ __launch_bounds__(256)
void attn_partial(const ushort_t* __restrict__ feat,
                  const ushort_t* __restrict__ mem,
                  const float* __restrict__ qw,
                  const float* __restrict__ v,
                  const int* __restrict__ mask,
                  float* __restrict__ pl, float* __restrict__ pacc) {
    const int gtid = blockIdx.x * 256 + threadIdx.x;
    const int wave = gtid >> 6;
    const int lane = threadIdx.x & 63;
    float qv[8], vv[8];
    {
        float4 q0 = *(const float4*)&qw[lane * 8];
        float4 q1 = *(const float4*)&qw[lane * 8 + 4];
        qv[0] = q0.x; qv[1] = q0.y; qv[2] = q0.z; qv[3] = q0.w;
        qv[4] = q1.x; qv[5] = q1.y; qv[6] = q1.z; qv[7] = q1.w;
        float4 v0 = *(const float4*)&v[lane * 8];
        float4 v1 = *(const float4*)&v[lane * 8 + 4];
        vv[0] = v0.x; vv[1] = v0.y; vv[2] = v0.z; vv[3] = v0.w;
        vv[4] = v1.x; vv[5] = v1.y; vv[6] = v1.z; vv[7] = v1.w;
    }
    // deterministic score bound C = sum_j |v_j|
    float C = 0.f;
#pragma unroll
    for (int j = 0; j < 8; ++j) C += fabsf(vv[j]);
#pragma unroll
    for (int off = 32; off; off >>= 1) C += __shfl_xor(C, off, 64);

    float lsum = 0.f;
    float acc[8];
#pragma unroll
    for (int j = 0; j < 8; ++j) acc[j] = 0.f;
    const int row0 = wave * RPW;

    uint4 fc = *(const uint4*)(feat + (size_t)row0 * HH + lane * 8);
    uint4 mc;
    if (!HOP) mc = *(const uint4*)(mem + (size_t)row0 * DD + lane * 8);
#pragma unroll 4
    for (int r = 0; r < RPW; ++r) {
        uint4 fn, mn;
        if (r + 1 < RPW) {
            fn = *(const uint4*)(feat + (size_t)(row0 + r + 1) * HH + lane * 8);
            if (!HOP) mn = *(const uint4*)(mem + (size_t)(row0 + r + 1) * DD + lane * 8);
        }
        float f[8];
        f[0] = bflo(fc.x); f[1] = bfhi(fc.x); f[2] = bflo(fc.y); f[3] = bfhi(fc.y);
        f[4] = bflo(fc.z); f[5] = bfhi(fc.z); f[6] = bflo(fc.w); f[7] = bfhi(fc.w);
        float mv[8];
        if (!HOP) {
            mv[0] = bflo(mc.x); mv[1] = bfhi(mc.x); mv[2] = bflo(mc.y); mv[3] = bfhi(mc.y);
            mv[4] = bflo(mc.z); mv[5] = bfhi(mc.z); mv[6] = bflo(mc.w); mv[7] = bfhi(mc.w);
        } else {
#pragma unroll
            for (int j = 0; j < 8; ++j) mv[j] = f[j];
        }
        float d = 0.f;
#pragma unroll
        for (int j = 0; j < 8; ++j) d += fast_tanh(f[j] + qv[j]) * vv[j];
#pragma unroll
        for (int off = 32; off; off >>= 1) d += __shfl_xor(d, off, 64);
        const float sc = d - C + (mask[row0 + r] ? 0.f : NEG_INFF);
        const float p = __expf(sc);
        lsum += p;
#pragma unroll
        for (int j = 0; j < 8; ++j) acc[j] += p * mv[j];
        fc = fn;
        if (!HOP) mc = mn;
    }
    const size_t base = (size_t)wave * HH + lane * 8;
    *(float4*)&pacc[base]     = make_float4(acc[0], acc[1], acc[2], acc[3]);
    *(float4*)&pacc[base + 4] = make_float4(acc[4], acc[5], acc[6], acc[7]);
    if (lane == 0) pl[wave] = lsum;
}

// ---------- attention phase B: plain sum of partials; grid 64 x 256 ----------
__global__ __launch_bounds__(256)
void attn_combine(const float* __restrict__ pl, const float* __restrict__ pacc,
                  float* __restrict__ out) {
    __shared__ float red[256];
    const int tid = threadIdx.x;
    const int lane = tid & 63, wv = tid >> 6;
    float lg = 0.f;
    for (int b = tid; b < NWAVE; b += 256) lg += pl[b];
#pragma unroll
    for (int off = 32; off; off >>= 1) lg += __shfl_xor(lg, off, 64);
    if (lane == 0) red[wv] = lg;
    __syncthreads();
    lg = red[0] + red[1] + red[2] + red[3];
    const float inv = 1.0f / lg;
    __syncthreads();
    const int c0 = blockIdx.x * 8;
    float a[8];
#pragma unroll
    for (int j = 0; j < 8; ++j) a[j] = 0.f;
    for (int b = tid; b < NWAVE; b += 256) {
        float4 p0 = *(const float4*)&pacc[(size_t)b * HH + c0];
        float4 p1 = *(const float4*)&pacc[(size_t)b * HH + c0 + 4];
        a[0] += p0.x; a[1] += p0.y; a[2] += p0.z; a[3] += p0.w;
        a[4] += p1.x; a[5] += p1.y; a[6] += p1.z; a[7] += p1.w;
    }
#pragma unroll
    for (int j = 0; j < 8; ++j)
#pragma unroll
        for (int off = 32; off; off >>= 1) a[j] += __shfl_xor(a[j], off, 64);
    if (lane == 0) {
#pragma unroll
        for (int j = 0; j < 8; ++j) red[wv * 8 + j] = a[j];
    }
    __syncthreads();
    if (tid < 8) {
        float s = red[tid] + red[8 + tid] + red[16 + tid] + red[24 + tid];
        out[c0 + tid] = s * inv;
    }
}

// ---------- score ----------
__global__ void score_k(const float* __restrict__ x, const float* __restrict__ sw,
                        const float* __restrict__ sb, float* __restrict__ out) {
    const int lane = threadIdx.x;   // 64
    float s = 0.f;
#pragma unroll
    for (int t = 0; t < 8; ++t) {
        int k = lane + 64 * t;
        s += x[k] * sw[k];
    }
#pragma unroll
    for (int off = 32; off; off >>= 1) s += __shfl_xor(s, off, 64);
    if (lane == 0) out[0] = s + sb[0];
}

// ---------- launcher ----------
extern "C" void kernel_launch(void* const* d_in, const int* in_sizes, int n_in,
                              void* d_out, int out_size, void* d_ws, size_t ws_size,
                              hipStream_t stream) {
    (void)in_sizes; (void)n_in; (void)out_size; (void)ws_size;
    const float* attn_mem = (const float*)d_in[0];
    const float* attn_wm  = (const float*)d_in[1];
    const float* attn_wq  = (const float*)d_in[2];
    const float* attn_v   = (const float*)d_in[3];
    const float* hop_wm   = (const float*)d_in[4];
    const float* hop_wq   = (const float*)d_in[5];
    const float* hop_v    = (const float*)d_in[6];
    const float* init_i   = (const float*)d_in[7];
    const float* init_h   = (const float*)d_in[8];
    const float* init_c   = (const float*)d_in[9];
    const float* w_ih     = (const float*)d_in[10];
    const float* w_hh     = (const float*)d_in[11];
    const float* b_ih     = (const float*)d_in[12];
    const float* b_hh     = (const float*)d_in[13];
    const float* score_w  = (const float*)d_in[14];
    const float* score_b  = (const float*)d_in[15];
    const int*   mask     = (const int*)d_in[16];
    float* dout = (float*)d_out;

    size_t off = 0;
    char* base = (char*)d_ws;
    auto carve = [&](size_t bytes) -> char* {
        char* p = base + off;
        off += (bytes + 255) & ~(size_t)255;
        return p;
    };
    ushort_t* Abf  = (ushort_t*)carve((size_t)NN * DD * 2);
    ushort_t* WT0  = (ushort_t*)carve((size_t)DD * HH * 2);
    ushort_t* WT1  = (ushort_t*)carve((size_t)DD * HH * 2);
    ushort_t* afeat = (ushort_t*)carve((size_t)NN * HH * 2);
    ushort_t* hfeat = (ushort_t*)carve((size_t)NN * HH * 2);
    float* pacc  = (float*)carve((size_t)NWAVE * HH * 4);
    float* pl    = (float*)carve((size_t)NWAVE * 4);
    float* gates = (float*)carve(4 * HH * 4);
    float* hbuf  = (float*)carve(HH * 4);
    float* cb0   = (float*)carve(HH * 4);
    float* cb1   = (float*)carve(HH * 4);
    float* qbuf  = (float*)carve(HH * 4);
    float* qwbuf = (float*)carve(HH * 4);
    float* xbuf  = (float*)carve(DD * 4);

    conv_bf16<<<(NN * DD / 8) / 256, 256, 0, stream>>>(attn_mem, Abf);
    conv_wt<<<dim3(128, 2), 256, 0, stream>>>(attn_wm, hop_wm, WT0, WT1);
    gemm_mfma<<<dim3(NN / TM, 8), 256, 0, stream>>>(Abf, WT0, WT1,
        (__hip_bfloat16*)afeat, (__hip_bfloat16*)hfeat);

    for (int s = 0; s < NSTEP; ++s) {
        const float* x   = s ? xbuf : init_i;
        const float* hin = s ? hbuf : init_h;
        const float* cin = s == 0 ? init_c : (s & 1 ? cb0 : cb1);
        float* cout      = (s & 1) ? cb1 : cb0;
        lstm_gates<<<512, 256, 0, stream>>>(x, hin, w_ih, w_hh, b_ih, b_hh, gates);
        lstm_tail<<<8, 512, 0, stream>>>(gates, cin, cout, hbuf, hop_wq, qwbuf);
        attn_partial<true><<<ABLOCKS, 256, 0, stream>>>(hfeat, nullptr, qwbuf, hop_v, mask, pl, pacc);
        attn_combine<<<64, 256, 0, stream>>>(pl, pacc, qbuf);
        vecmat512<<<8, 512, 0, stream>>>(qbuf, attn_wq, qwbuf);
        attn_partial<false><<<ABLOCKS, 256, 0, stream>>>(afeat, Abf, qwbuf, attn_v, mask, pl, pacc);
        attn_combine<<<64, 256, 0, stream>>>(pl, pacc, xbuf);
        score_k<<<1, 64, 0, stream>>>(xbuf, score_w, score_b, dout + s);
    }
}

// Round 5
// 509.421 us; speedup vs baseline: 2.6765x; 1.0120x over previous
//
#include <hip/hip_runtime.h>
#include <hip/hip_bf16.h>

#define NN 65536
#define DD 512
#define HH 512
#define NSTEP 4
#define NEG_INFF -100000000.0f

#define RPW 16                 // rows per wave in attn_partial
#define ABLOCKS 1024
#define NWAVE (ABLOCKS * 4)    // 4096 waves x 16 rows = 65536

typedef unsigned short ushort_t;
typedef __attribute__((ext_vector_type(8))) short bf16x8;
typedef __attribute__((ext_vector_type(4))) float f32x4;

// ---------- helpers ----------
__device__ __forceinline__ float bflo(unsigned u) {
    union { unsigned i; float f; } v; v.i = u << 16; return v.f;
}
__device__ __forceinline__ float bfhi(unsigned u) {
    union { unsigned i; float f; } v; v.i = u & 0xffff0000u; return v.f;
}
__device__ __forceinline__ float fast_tanh(float x) {
    float e = __expf(2.0f * x);
    return 1.0f - 2.0f * __builtin_amdgcn_rcpf(e + 1.0f);
}

#define GL2LDS(g, l) __builtin_amdgcn_global_load_lds( \
    (const __attribute__((address_space(1))) unsigned int*)(g), \
    (__attribute__((address_space(3))) unsigned int*)(l), 16, 0, 0)

// ---------- f32 -> bf16 convert (attn_mem) ----------
__global__ __launch_bounds__(256)
void conv_bf16(const float* __restrict__ in, ushort_t* __restrict__ out) {
    const int i = blockIdx.x * 256 + threadIdx.x;
    const size_t base = (size_t)i * 8;
    float4 a = *(const float4*)&in[base];
    float4 b = *(const float4*)&in[base + 4];
    union { __hip_bfloat16 h[8]; uint4 u; } t;
    t.h[0] = __float2bfloat16(a.x); t.h[1] = __float2bfloat16(a.y);
    t.h[2] = __float2bfloat16(a.z); t.h[3] = __float2bfloat16(a.w);
    t.h[4] = __float2bfloat16(b.x); t.h[5] = __float2bfloat16(b.y);
    t.h[6] = __float2bfloat16(b.z); t.h[7] = __float2bfloat16(b.w);
    *(uint4*)&out[base] = t.u;
}

// ---------- weight transpose + convert: WT[n][k] = bf16(W[k][n]) ----------
__global__ __launch_bounds__(256)
void conv_wt(const float* __restrict__ W0, const float* __restrict__ W1,
             ushort_t* __restrict__ T0, ushort_t* __restrict__ T1) {
    const float* W = blockIdx.y ? W1 : W0;
    ushort_t* T = blockIdx.y ? T1 : T0;
    const int n = blockIdx.x * 4 + (threadIdx.x >> 6);
    const int k0 = (threadIdx.x & 63) * 8;
    union { __hip_bfloat16 h[8]; uint4 u; } t;
#pragma unroll
    for (int i = 0; i < 8; ++i)
        t.h[i] = __float2bfloat16(W[(size_t)(k0 + i) * HH + n]);
    *(uint4*)&T[(size_t)n * DD + k0] = t.u;
}

// ---------- MFMA GEMM, XCD-locality swizzled grid (4096 linear blocks) ----------
// XCD k (= blockIdx.x % 8) owns M-tiles [64k, 64k+64); the 8 N-slices of one
// M-tile are consecutive same-XCD dispatch slots -> A-panel (128KB) L2-resident.
#define TM 128
#define TK 32
__global__ __launch_bounds__(256)
void gemm_mfma(const ushort_t* __restrict__ A,
               const ushort_t* __restrict__ WT0, const ushort_t* __restrict__ WT1,
               __hip_bfloat16* __restrict__ C0, __hip_bfloat16* __restrict__ C1) {
    __shared__ ushort_t As[TM * TK];
    __shared__ ushort_t Bs[TM * TK];
    const int L = blockIdx.x;
    const int xcd = L & 7;
    const int slot = L >> 3;                  // 0..511
    const int mt = xcd * 64 + (slot >> 3);    // M-tile 0..511
    const int my = slot & 7;                  // N-slice 0..7
    const ushort_t* WT = (my < 4) ? WT0 : WT1;
    __hip_bfloat16* Cp = (my < 4) ? C0 : C1;
    const int bn = (my & 3) * TM;
    const int bm = mt * TM;
    const int tid = threadIdx.x;
    const int lane = tid & 63;
    const int wid = tid >> 6;
    const int wr = (wid >> 1) * 64;
    const int wc = (wid & 1) * 64;
    const int l15 = lane & 15;
    const int srow = lane >> 2;
    const int ske = (((lane & 3) ^ ((lane >> 3) & 3)) * 8);
    const int koff = (((lane >> 4) ^ ((l15 >> 1) & 3)) << 3);

    const f32x4 zero = {0.f, 0.f, 0.f, 0.f};
    f32x4 acc[4][4];
#pragma unroll
    for (int m = 0; m < 4; ++m)
#pragma unroll
        for (int n = 0; n < 4; ++n) acc[m][n] = zero;

    for (int k0 = 0; k0 < DD; k0 += TK) {
        __syncthreads();
#pragma unroll
        for (int u = 0; u < 2; ++u) {
            const int g = u * 4 + wid;
            const int row = g * 16 + srow;
            GL2LDS(A + (size_t)(bm + row) * DD + k0 + ske, As + g * 512);
            GL2LDS(WT + (size_t)(bn + row) * DD + k0 + ske, Bs + g * 512);
        }
        __syncthreads();
        bf16x8 af[4], bfr[4];
#pragma unroll
        for (int m = 0; m < 4; ++m)
            af[m] = *(const bf16x8*)(As + (wr + m * 16 + l15) * TK + koff);
#pragma unroll
        for (int n = 0; n < 4; ++n)
            bfr[n] = *(const bf16x8*)(Bs + (wc + n * 16 + l15) * TK + koff);
#pragma unroll
        for (int m = 0; m < 4; ++m)
#pragma unroll
            for (int n = 0; n < 4; ++n)
                acc[m][n] = __builtin_amdgcn_mfma_f32_16x16x32_bf16(af[m], bfr[n], acc[m][n], 0, 0, 0);
    }
    const int r0 = (lane >> 4) * 4;
#pragma unroll
    for (int m = 0; m < 4; ++m) {
#pragma unroll
        for (int n = 0; n < 4; ++n) {
            const f32x4 vv = acc[m][n];
            const size_t cb = (size_t)(bm + wr + m * 16 + r0) * HH + bn + wc + n * 16 + l15;
#pragma unroll
            for (int r = 0; r < 4; ++r)
                Cp[cb + (size_t)r * HH] = __float2bfloat16(vv[r]);
        }
    }
}

// ---------- LSTM gates ----------
__global__ __launch_bounds__(256)
void lstm_gates(const float* __restrict__ x, const float* __restrict__ h,
                const float* __restrict__ w_ih, const float* __restrict__ w_hh,
                const float* __restrict__ b_ih, const float* __restrict__ b_hh,
                float* __restrict__ gates) {
    const int wave = (blockIdx.x * 256 + threadIdx.x) >> 6;
    const int lane = threadIdx.x & 63;
    const float* wi = w_ih + (size_t)wave * DD;
    const float* wh = w_hh + (size_t)wave * HH;
    float s = 0.f;
#pragma unroll
    for (int t = 0; t < 8; ++t) {
        int k = lane + 64 * t;
        s += wi[k] * x[k] + wh[k] * h[k];
    }
#pragma unroll
    for (int off = 32; off; off >>= 1) s += __shfl_xor(s, off, 64);
    if (lane == 0) gates[wave] = s + b_ih[wave] + b_hh[wave];
}

// ---------- fused LSTM h/c + qw = h @ hop_wq ----------
__global__ __launch_bounds__(512)
void lstm_tail(const float* __restrict__ gates, const float* __restrict__ cin,
               float* __restrict__ cout, float* __restrict__ hout,
               const float* __restrict__ Wq, float* __restrict__ qwout) {
    __shared__ float hs[HH];
    __shared__ float red[8][64];
    const int j = threadIdx.x;
    {
        float ig = gates[j], fg = gates[HH + j], gg = gates[2 * HH + j], og = gates[3 * HH + j];
        float si = 1.f / (1.f + __expf(-ig));
        float sf = 1.f / (1.f + __expf(-fg));
        float so = 1.f / (1.f + __expf(-og));
        float cn = sf * cin[j] + si * tanhf(gg);
        float hn = so * tanhf(cn);
        hs[j] = hn;
        if (blockIdx.x == 0) { cout[j] = cn; hout[j] = hn; }
    }
    __syncthreads();
    const int lane = threadIdx.x & 63, wv = threadIdx.x >> 6;
    const int col = blockIdx.x * 64 + lane;
    float s = 0.f;
    const int k0 = wv * 64;
#pragma unroll 4
    for (int k = k0; k < k0 + 64; ++k) s += hs[k] * Wq[(size_t)k * HH + col];
    red[wv][lane] = s;
    __syncthreads();
    if (wv == 0) {
        float t = 0.f;
#pragma unroll
        for (int r = 0; r < 8; ++r) t += red[r][lane];
        qwout[col] = t;
    }
}

// ---------- qw = q @ W (512x512), grid 8 x 512 ----------
__global__ __launch_bounds__(512)
void vecmat512(const float* __restrict__ q, const float* __restrict__ W,
               float* __restrict__ out) {
    __shared__ float red[8][64];
    const int lane = threadIdx.x & 63, wv = threadIdx.x >> 6;
    const int j = blockIdx.x * 64 + lane;
    float s = 0.f;
    const int k0 = wv * 64;
#pragma unroll 4
    for (int k = k0; k < k0 + 64; ++k) s += q[k] * W[(size_t)k * HH + j];
    red[wv][lane] = s;
    __syncthreads();
    if (wv == 0) {
        float t = 0.f;
#pragma unroll
        for (int r = 0; r < 8; ++r) t += red[r][lane];
        out[j] = t;
    }
}

// ---------- attention phase A: fixed-offset exp partials ----------
// softmax(sc) = exp(sc-C)/sum exp(sc-C) with C = sum|v| >= max sc (tanh in [-1,1])
template<bool HOP>
__global__ __launch_bounds__(256)
void attn_partial(const ushort_t* __restrict__ feat,
                  const ushort_t* __restrict__ mem,
                  const float* __restrict__ qw,
                  const float* __restrict__ v,
                  const int* __restrict__ mask,
                  float* __restrict__ pl, float* __restrict__ pacc) {
    const int gtid = blockIdx.x * 256 + threadIdx.x;
    const int wave = gtid >> 6;
    const int lane = threadIdx.x & 63;
    float qv[8], vv[8];
    {
        float4 q0 = *(const float4*)&qw[lane * 8];
        float4 q1 = *(const float4*)&qw[lane * 8 + 4];
        qv[0] = q0.x; qv[1] = q0.y; qv[2] = q0.z; qv[3] = q0.w;
        qv[4] = q1.x; qv[5] = q1.y; qv[6] = q1.z; qv[7] = q1.w;
        float4 v0 = *(const float4*)&v[lane * 8];
        float4 v1 = *(const float4*)&v[lane * 8 + 4];
        vv[0] = v0.x; vv[1] = v0.y; vv[2] = v0.z; vv[3] = v0.w;
        vv[4] = v1.x; vv[5] = v1.y; vv[6] = v1.z; vv[7] = v1.w;
    }
    float C = 0.f;
#pragma unroll
    for (int j = 0; j < 8; ++j) C += fabsf(vv[j]);
#pragma unroll
    for (int off = 32; off; off >>= 1) C += __shfl_xor(C, off, 64);

    float lsum = 0.f;
    float acc[8];
#pragma unroll
    for (int j = 0; j < 8; ++j) acc[j] = 0.f;
    const int row0 = wave * RPW;

    uint4 fc = *(const uint4*)(feat + (size_t)row0 * HH + lane * 8);
    uint4 mc;
    if (!HOP) mc = *(const uint4*)(mem + (size_t)row0 * DD + lane * 8);
#pragma unroll 4
    for (int r = 0; r < RPW; ++r) {
        uint4 fn, mn;
        if (r + 1 < RPW) {
            fn = *(const uint4*)(feat + (size_t)(row0 + r + 1) * HH + lane * 8);
            if (!HOP) mn = *(const uint4*)(mem + (size_t)(row0 + r + 1) * DD + lane * 8);
        }
        float f[8];
        f[0] = bflo(fc.x); f[1] = bfhi(fc.x); f[2] = bflo(fc.y); f[3] = bfhi(fc.y);
        f[4] = bflo(fc.z); f[5] = bfhi(fc.z); f[6] = bflo(fc.w); f[7] = bfhi(fc.w);
        float mv[8];
        if (!HOP) {
            mv[0] = bflo(mc.x); mv[1] = bfhi(mc.x); mv[2] = bflo(mc.y); mv[3] = bfhi(mc.y);
            mv[4] = bflo(mc.z); mv[5] = bfhi(mc.z); mv[6] = bflo(mc.w); mv[7] = bfhi(mc.w);
        } else {
#pragma unroll
            for (int j = 0; j < 8; ++j) mv[j] = f[j];
        }
        float d = 0.f;
#pragma unroll
        for (int j = 0; j < 8; ++j) d += fast_tanh(f[j] + qv[j]) * vv[j];
#pragma unroll
        for (int off = 32; off; off >>= 1) d += __shfl_xor(d, off, 64);
        const float sc = d - C + (mask[row0 + r] ? 0.f : NEG_INFF);
        const float p = __expf(sc);
        lsum += p;
#pragma unroll
        for (int j = 0; j < 8; ++j) acc[j] += p * mv[j];
        fc = fn;
        if (!HOP) mc = mn;
    }
    const size_t base = (size_t)wave * HH + lane * 8;
    *(float4*)&pacc[base]     = make_float4(acc[0], acc[1], acc[2], acc[3]);
    *(float4*)&pacc[base + 4] = make_float4(acc[4], acc[5], acc[6], acc[7]);
    if (lane == 0) pl[wave] = lsum;
}

// ---------- attention phase B: plain sum of partials; grid 64 x 256 ----------
__global__ __launch_bounds__(256)
void attn_combine(const float* __restrict__ pl, const float* __restrict__ pacc,
                  float* __restrict__ out) {
    __shared__ float red[256];
    const int tid = threadIdx.x;
    const int lane = tid & 63, wv = tid >> 6;
    float lg = 0.f;
    for (int b = tid; b < NWAVE; b += 256) lg += pl[b];
#pragma unroll
    for (int off = 32; off; off >>= 1) lg += __shfl_xor(lg, off, 64);
    if (lane == 0) red[wv] = lg;
    __syncthreads();
    lg = red[0] + red[1] + red[2] + red[3];
    const float inv = 1.0f / lg;
    __syncthreads();
    const int c0 = blockIdx.x * 8;
    float a[8];
#pragma unroll
    for (int j = 0; j < 8; ++j) a[j] = 0.f;
    for (int b = tid; b < NWAVE; b += 256) {
        float4 p0 = *(const float4*)&pacc[(size_t)b * HH + c0];
        float4 p1 = *(const float4*)&pacc[(size_t)b * HH + c0 + 4];
        a[0] += p0.x; a[1] += p0.y; a[2] += p0.z; a[3] += p0.w;
        a[4] += p1.x; a[5] += p1.y; a[6] += p1.z; a[7] += p1.w;
    }
#pragma unroll
    for (int j = 0; j < 8; ++j)
#pragma unroll
        for (int off = 32; off; off >>= 1) a[j] += __shfl_xor(a[j], off, 64);
    if (lane == 0) {
#pragma unroll
        for (int j = 0; j < 8; ++j) red[wv * 8 + j] = a[j];
    }
    __syncthreads();
    if (tid < 8) {
        float s = red[tid] + red[8 + tid] + red[16 + tid] + red[24 + tid];
        out[c0 + tid] = s * inv;
    }
}

// ---------- score ----------
__global__ void score_k(const float* __restrict__ x, const float* __restrict__ sw,
                        const float* __restrict__ sb, float* __restrict__ out) {
    const int lane = threadIdx.x;   // 64
    float s = 0.f;
#pragma unroll
    for (int t = 0; t < 8; ++t) {
        int k = lane + 64 * t;
        s += x[k] * sw[k];
    }
#pragma unroll
    for (int off = 32; off; off >>= 1) s += __shfl_xor(s, off, 64);
    if (lane == 0) out[0] = s + sb[0];
}

// ---------- launcher ----------
extern "C" void kernel_launch(void* const* d_in, const int* in_sizes, int n_in,
                              void* d_out, int out_size, void* d_ws, size_t ws_size,
                              hipStream_t stream) {
    (void)in_sizes; (void)n_in; (void)out_size; (void)ws_size;
    const float* attn_mem = (const float*)d_in[0];
    const float* attn_wm  = (const float*)d_in[1];
    const float* attn_wq  = (const float*)d_in[2];
    const float* attn_v   = (const float*)d_in[3];
    const float* hop_wm   = (const float*)d_in[4];
    const float* hop_wq   = (const float*)d_in[5];
    const float* hop_v    = (const float*)d_in[6];
    const float* init_i   = (const float*)d_in[7];
    const float* init_h   = (const float*)d_in[8];
    const float* init_c   = (const float*)d_in[9];
    const float* w_ih     = (const float*)d_in[10];
    const float* w_hh     = (const float*)d_in[11];
    const float* b_ih     = (const float*)d_in[12];
    const float* b_hh     = (const float*)d_in[13];
    const float* score_w  = (const float*)d_in[14];
    const float* score_b  = (const float*)d_in[15];
    const int*   mask     = (const int*)d_in[16];
    float* dout = (float*)d_out;

    size_t off = 0;
    char* base = (char*)d_ws;
    auto carve = [&](size_t bytes) -> char* {
        char* p = base + off;
        off += (bytes + 255) & ~(size_t)255;
        return p;
    };
    ushort_t* Abf  = (ushort_t*)carve((size_t)NN * DD * 2);
    ushort_t* WT0  = (ushort_t*)carve((size_t)DD * HH * 2);
    ushort_t* WT1  = (ushort_t*)carve((size_t)DD * HH * 2);
    ushort_t* afeat = (ushort_t*)carve((size_t)NN * HH * 2);
    ushort_t* hfeat = (ushort_t*)carve((size_t)NN * HH * 2);
    float* pacc  = (float*)carve((size_t)NWAVE * HH * 4);
    float* pl    = (float*)carve((size_t)NWAVE * 4);
    float* gates = (float*)carve(4 * HH * 4);
    float* hbuf  = (float*)carve(HH * 4);
    float* cb0   = (float*)carve(HH * 4);
    float* cb1   = (float*)carve(HH * 4);
    float* qbuf  = (float*)carve(HH * 4);
    float* qwbuf = (float*)carve(HH * 4);
    float* xbuf  = (float*)carve(DD * 4);

    conv_bf16<<<(NN * DD / 8) / 256, 256, 0, stream>>>(attn_mem, Abf);
    conv_wt<<<dim3(128, 2), 256, 0, stream>>>(attn_wm, hop_wm, WT0, WT1);
    gemm_mfma<<<4096, 256, 0, stream>>>(Abf, WT0, WT1,
        (__hip_bfloat16*)afeat, (__hip_bfloat16*)hfeat);

    for (int s = 0; s < NSTEP; ++s) {
        const float* x   = s ? xbuf : init_i;
        const float* hin = s ? hbuf : init_h;
        const float* cin = s == 0 ? init_c : (s & 1 ? cb0 : cb1);
        float* cout      = (s & 1) ? cb1 : cb0;
        lstm_gates<<<512, 256, 0, stream>>>(x, hin, w_ih, w_hh, b_ih, b_hh, gates);
        lstm_tail<<<8, 512, 0, stream>>>(gates, cin, cout, hbuf, hop_wq, qwbuf);
        attn_partial<true><<<ABLOCKS, 256, 0, stream>>>(hfeat, nullptr, qwbuf, hop_v, mask, pl, pacc);
        attn_combine<<<64, 256, 0, stream>>>(pl, pacc, qbuf);
        vecmat512<<<8, 512, 0, stream>>>(qbuf, attn_wq, qwbuf);
        attn_partial<false><<<ABLOCKS, 256, 0, stream>>>(afeat, Abf, qwbuf, attn_v, mask, pl, pacc);
        attn_combine<<<64, 256, 0, stream>>>(pl, pacc, xbuf);
        score_k<<<1, 64, 0, stream>>>(xbuf, score_w, score_b, dout + s);
    }
}

// Round 6
// 501.844 us; speedup vs baseline: 2.7169x; 1.0151x over previous
//
#include <hip/hip_runtime.h>
#include <hip/hip_bf16.h>

#define NN 65536
#define DD 512
#define HH 512
#define NSTEP 4
#define NEG_INFF -100000000.0f

#define RPW 16                 // rows per wave in attn_partial
#define ABLOCKS 1024
#define NWAVE (ABLOCKS * 4)    // 4096 waves x 16 rows = 65536

typedef unsigned short ushort_t;
typedef __attribute__((ext_vector_type(8))) short bf16x8;
typedef __attribute__((ext_vector_type(4))) float f32x4;

// ---------- helpers ----------
__device__ __forceinline__ float bflo(unsigned u) {
    union { unsigned i; float f; } v; v.i = u << 16; return v.f;
}
__device__ __forceinline__ float bfhi(unsigned u) {
    union { unsigned i; float f; } v; v.i = u & 0xffff0000u; return v.f;
}
__device__ __forceinline__ float fast_tanh(float x) {
    float e = __expf(2.0f * x);
    return 1.0f - 2.0f * __builtin_amdgcn_rcpf(e + 1.0f);
}

#define GL2LDS(g, l) __builtin_amdgcn_global_load_lds( \
    (const __attribute__((address_space(1))) unsigned int*)(g), \
    (__attribute__((address_space(3))) unsigned int*)(l), 16, 0, 0)

// ---------- f32 -> bf16 convert (attn_mem) ----------
__global__ __launch_bounds__(256)
void conv_bf16(const float* __restrict__ in, ushort_t* __restrict__ out) {
    const int i = blockIdx.x * 256 + threadIdx.x;
    const size_t base = (size_t)i * 8;
    float4 a = *(const float4*)&in[base];
    float4 b = *(const float4*)&in[base + 4];
    union { __hip_bfloat16 h[8]; uint4 u; } t;
    t.h[0] = __float2bfloat16(a.x); t.h[1] = __float2bfloat16(a.y);
    t.h[2] = __float2bfloat16(a.z); t.h[3] = __float2bfloat16(a.w);
    t.h[4] = __float2bfloat16(b.x); t.h[5] = __float2bfloat16(b.y);
    t.h[6] = __float2bfloat16(b.z); t.h[7] = __float2bfloat16(b.w);
    *(uint4*)&out[base] = t.u;
}

// ---------- weight transpose + convert: WT[n][k] = bf16(W[k][n]) ----------
__global__ __launch_bounds__(256)
void conv_wt(const float* __restrict__ W0, const float* __restrict__ W1,
             ushort_t* __restrict__ T0, ushort_t* __restrict__ T1) {
    const float* W = blockIdx.y ? W1 : W0;
    ushort_t* T = blockIdx.y ? T1 : T0;
    const int n = blockIdx.x * 4 + (threadIdx.x >> 6);
    const int k0 = (threadIdx.x & 63) * 8;
    union { __hip_bfloat16 h[8]; uint4 u; } t;
#pragma unroll
    for (int i = 0; i < 8; ++i)
        t.h[i] = __float2bfloat16(W[(size_t)(k0 + i) * HH + n]);
    *(uint4*)&T[(size_t)n * DD + k0] = t.u;
}

// ---------- MFMA GEMM: XCD-locality grid + 2-phase LDS double-buffer ----------
// T3-minimum pipeline: stage(t+2) after compute(t); counted vmcnt(4) (never 0
// mid-loop); raw s_barrier (NOT __syncthreads -> would re-insert vmcnt(0) drain).
#define TM 128
#define TK 32
#define NT (DD / TK)   // 16 K-steps
__global__ __launch_bounds__(256)
void gemm_mfma(const ushort_t* __restrict__ A,
               const ushort_t* __restrict__ WT0, const ushort_t* __restrict__ WT1,
               __hip_bfloat16* __restrict__ C0, __hip_bfloat16* __restrict__ C1) {
    __shared__ ushort_t As[2][TM * TK];
    __shared__ ushort_t Bs[2][TM * TK];
    const int L = blockIdx.x;
    const int xcd = L & 7;
    const int slot = L >> 3;                  // 0..511
    const int mt = xcd * 64 + (slot >> 3);    // M-tile 0..511
    const int my = slot & 7;                  // N-slice 0..7
    const ushort_t* WT = (my < 4) ? WT0 : WT1;
    __hip_bfloat16* Cp = (my < 4) ? C0 : C1;
    const int bn = (my & 3) * TM;
    const int bm = mt * TM;
    const int tid = threadIdx.x;
    const int lane = tid & 63;
    const int wid = tid >> 6;
    const int wr = (wid >> 1) * 64;
    const int wc = (wid & 1) * 64;
    const int l15 = lane & 15;
    const int srow = lane >> 2;
    const int ske = (((lane & 3) ^ ((lane >> 3) & 3)) * 8);
    const int koff = (((lane >> 4) ^ ((l15 >> 1) & 3)) << 3);

    const ushort_t* Abase = A + (size_t)bm * DD;
    const ushort_t* Bbase = WT + (size_t)bn * DD;

    // stage one K-tile into buffer b: 4 global_load_lds per thread
    auto stage = [&](int b, int k0) {
#pragma unroll
        for (int u = 0; u < 2; ++u) {
            const int g = u * 4 + wid;
            const int row = g * 16 + srow;
            GL2LDS(Abase + (size_t)row * DD + k0 + ske, &As[b][g * 512]);
            GL2LDS(Bbase + (size_t)row * DD + k0 + ske, &Bs[b][g * 512]);
        }
    };

    const f32x4 zero = {0.f, 0.f, 0.f, 0.f};
    f32x4 acc[4][4];
#pragma unroll
    for (int m = 0; m < 4; ++m)
#pragma unroll
        for (int n = 0; n < 4; ++n) acc[m][n] = zero;

    // prologue: two K-tiles in flight
    stage(0, 0);
    stage(1, TK);
    __builtin_amdgcn_sched_barrier(0);

    for (int t = 0; t < NT; ++t) {
        const int cur = t & 1;
        // wait for stage(t): it is the oldest 4 of (up to) 8 outstanding loads
        if (t + 1 < NT) asm volatile("s_waitcnt vmcnt(4)" ::: "memory");
        else            asm volatile("s_waitcnt vmcnt(0)" ::: "memory");
        __builtin_amdgcn_sched_barrier(0);
        __builtin_amdgcn_s_barrier();
        __builtin_amdgcn_sched_barrier(0);

        bf16x8 af[4], bfr[4];
#pragma unroll
        for (int m = 0; m < 4; ++m)
            af[m] = *(const bf16x8*)(&As[cur][(wr + m * 16 + l15) * TK + koff]);
#pragma unroll
        for (int n = 0; n < 4; ++n)
            bfr[n] = *(const bf16x8*)(&Bs[cur][(wc + n * 16 + l15) * TK + koff]);
#pragma unroll
        for (int m = 0; m < 4; ++m)
#pragma unroll
            for (int n = 0; n < 4; ++n)
                acc[m][n] = __builtin_amdgcn_mfma_f32_16x16x32_bf16(af[m], bfr[n], acc[m][n], 0, 0, 0);

        // all this wave's ds_reads of buf[cur] retired before signaling
        asm volatile("s_waitcnt lgkmcnt(0)" ::: "memory");
        __builtin_amdgcn_sched_barrier(0);
        __builtin_amdgcn_s_barrier();
        __builtin_amdgcn_sched_barrier(0);
        if (t + 2 < NT) stage(cur, (t + 2) * TK);
        __builtin_amdgcn_sched_barrier(0);
    }

    const int r0 = (lane >> 4) * 4;
#pragma unroll
    for (int m = 0; m < 4; ++m) {
#pragma unroll
        for (int n = 0; n < 4; ++n) {
            const f32x4 vv = acc[m][n];
            const size_t cb = (size_t)(bm + wr + m * 16 + r0) * HH + bn + wc + n * 16 + l15;
#pragma unroll
            for (int r = 0; r < 4; ++r)
                Cp[cb + (size_t)r * HH] = __float2bfloat16(vv[r]);
        }
    }
}

// ---------- LSTM gates ----------
__global__ __launch_bounds__(256)
void lstm_gates(const float* __restrict__ x, const float* __restrict__ h,
                const float* __restrict__ w_ih, const float* __restrict__ w_hh,
                const float* __restrict__ b_ih, const float* __restrict__ b_hh,
                float* __restrict__ gates) {
    const int wave = (blockIdx.x * 256 + threadIdx.x) >> 6;
    const int lane = threadIdx.x & 63;
    const float* wi = w_ih + (size_t)wave * DD;
    const float* wh = w_hh + (size_t)wave * HH;
    float s = 0.f;
#pragma unroll
    for (int t = 0; t < 8; ++t) {
        int k = lane + 64 * t;
        s += wi[k] * x[k] + wh[k] * h[k];
    }
#pragma unroll
    for (int off = 32; off; off >>= 1) s += __shfl_xor(s, off, 64);
    if (lane == 0) gates[wave] = s + b_ih[wave] + b_hh[wave];
}

// ---------- fused LSTM h/c + qw = h @ hop_wq ----------
__global__ __launch_bounds__(512)
void lstm_tail(const float* __restrict__ gates, const float* __restrict__ cin,
               float* __restrict__ cout, float* __restrict__ hout,
               const float* __restrict__ Wq, float* __restrict__ qwout) {
    __shared__ float hs[HH];
    __shared__ float red[8][64];
    const int j = threadIdx.x;
    {
        float ig = gates[j], fg = gates[HH + j], gg = gates[2 * HH + j], og = gates[3 * HH + j];
        float si = 1.f / (1.f + __expf(-ig));
        float sf = 1.f / (1.f + __expf(-fg));
        float so = 1.f / (1.f + __expf(-og));
        float cn = sf * cin[j] + si * tanhf(gg);
        float hn = so * tanhf(cn);
        hs[j] = hn;
        if (blockIdx.x == 0) { cout[j] = cn; hout[j] = hn; }
    }
    __syncthreads();
    const int lane = threadIdx.x & 63, wv = threadIdx.x >> 6;
    const int col = blockIdx.x * 64 + lane;
    float s = 0.f;
    const int k0 = wv * 64;
#pragma unroll 4
    for (int k = k0; k < k0 + 64; ++k) s += hs[k] * Wq[(size_t)k * HH + col];
    red[wv][lane] = s;
    __syncthreads();
    if (wv == 0) {
        float t = 0.f;
#pragma unroll
        for (int r = 0; r < 8; ++r) t += red[r][lane];
        qwout[col] = t;
    }
}

// ---------- qw = q @ W (512x512), grid 8 x 512 ----------
__global__ __launch_bounds__(512)
void vecmat512(const float* __restrict__ q, const float* __restrict__ W,
               float* __restrict__ out) {
    __shared__ float red[8][64];
    const int lane = threadIdx.x & 63, wv = threadIdx.x >> 6;
    const int j = blockIdx.x * 64 + lane;
    float s = 0.f;
    const int k0 = wv * 64;
#pragma unroll 4
    for (int k = k0; k < k0 + 64; ++k) s += q[k] * W[(size_t)k * HH + j];
    red[wv][lane] = s;
    __syncthreads();
    if (wv == 0) {
        float t = 0.f;
#pragma unroll
        for (int r = 0; r < 8; ++r) t += red[r][lane];
        out[j] = t;
    }
}

// ---------- attention phase A: fixed-offset exp partials ----------
// softmax(sc) = exp(sc-C)/sum exp(sc-C) with C = sum|v| >= max sc (tanh in [-1,1])
template<bool HOP>
__global__ __launch_bounds__(256)
void attn_partial(const ushort_t* __restrict__ feat,
                  const ushort_t* __restrict__ mem,
                  const float* __restrict__ qw,
                  const float* __restrict__ v,
                  const int* __restrict__ mask,
                  float* __restrict__ pl, float* __restrict__ pacc) {
    const int gtid = blockIdx.x * 256 + threadIdx.x;
    const int wave = gtid >> 6;
    const int lane = threadIdx.x & 63;
    float qv[8], vv[8];
    {
        float4 q0 = *(const float4*)&qw[lane * 8];
        float4 q1 = *(const float4*)&qw[lane * 8 + 4];
        qv[0] = q0.x; qv[1] = q0.y; qv[2] = q0.z; qv[3] = q0.w;
        qv[4] = q1.x; qv[5] = q1.y; qv[6] = q1.z; qv[7] = q1.w;
        float4 v0 = *(const float4*)&v[lane * 8];
        float4 v1 = *(const float4*)&v[lane * 8 + 4];
        vv[0] = v0.x; vv[1] = v0.y; vv[2] = v0.z; vv[3] = v0.w;
        vv[4] = v1.x; vv[5] = v1.y; vv[6] = v1.z; vv[7] = v1.w;
    }
    float C = 0.f;
#pragma unroll
    for (int j = 0; j < 8; ++j) C += fabsf(vv[j]);
#pragma unroll
    for (int off = 32; off; off >>= 1) C += __shfl_xor(C, off, 64);

    float lsum = 0.f;
    float acc[8];
#pragma unroll
    for (int j = 0; j < 8; ++j) acc[j] = 0.f;
    const int row0 = wave * RPW;

    uint4 fc = *(const uint4*)(feat + (size_t)row0 * HH + lane * 8);
    uint4 mc;
    if (!HOP) mc = *(const uint4*)(mem + (size_t)row0 * DD + lane * 8);
#pragma unroll 4
    for (int r = 0; r < RPW; ++r) {
        uint4 fn, mn;
        if (r + 1 < RPW) {
            fn = *(const uint4*)(feat + (size_t)(row0 + r + 1) * HH + lane * 8);
            if (!HOP) mn = *(const uint4*)(mem + (size_t)(row0 + r + 1) * DD + lane * 8);
        }
        float f[8];
        f[0] = bflo(fc.x); f[1] = bfhi(fc.x); f[2] = bflo(fc.y); f[3] = bfhi(fc.y);
        f[4] = bflo(fc.z); f[5] = bfhi(fc.z); f[6] = bflo(fc.w); f[7] = bfhi(fc.w);
        float mv[8];
        if (!HOP) {
            mv[0] = bflo(mc.x); mv[1] = bfhi(mc.x); mv[2] = bflo(mc.y); mv[3] = bfhi(mc.y);
            mv[4] = bflo(mc.z); mv[5] = bfhi(mc.z); mv[6] = bflo(mc.w); mv[7] = bfhi(mc.w);
        } else {
#pragma unroll
            for (int j = 0; j < 8; ++j) mv[j] = f[j];
        }
        float d = 0.f;
#pragma unroll
        for (int j = 0; j < 8; ++j) d += fast_tanh(f[j] + qv[j]) * vv[j];
#pragma unroll
        for (int off = 32; off; off >>= 1) d += __shfl_xor(d, off, 64);
        const float sc = d - C + (mask[row0 + r] ? 0.f : NEG_INFF);
        const float p = __expf(sc);
        lsum += p;
#pragma unroll
        for (int j = 0; j < 8; ++j) acc[j] += p * mv[j];
        fc = fn;
        if (!HOP) mc = mn;
    }
    const size_t base = (size_t)wave * HH + lane * 8;
    *(float4*)&pacc[base]     = make_float4(acc[0], acc[1], acc[2], acc[3]);
    *(float4*)&pacc[base + 4] = make_float4(acc[4], acc[5], acc[6], acc[7]);
    if (lane == 0) pl[wave] = lsum;
}

// ---------- attention phase B: plain sum of partials; grid 64 x 256 ----------
__global__ __launch_bounds__(256)
void attn_combine(const float* __restrict__ pl, const float* __restrict__ pacc,
                  float* __restrict__ out) {
    __shared__ float red[256];
    const int tid = threadIdx.x;
    const int lane = tid & 63, wv = tid >> 6;
    float lg = 0.f;
    for (int b = tid; b < NWAVE; b += 256) lg += pl[b];
#pragma unroll
    for (int off = 32; off; off >>= 1) lg += __shfl_xor(lg, off, 64);
    if (lane == 0) red[wv] = lg;
    __syncthreads();
    lg = red[0] + red[1] + red[2] + red[3];
    const float inv = 1.0f / lg;
    __syncthreads();
    const int c0 = blockIdx.x * 8;
    float a[8];
#pragma unroll
    for (int j = 0; j < 8; ++j) a[j] = 0.f;
    for (int b = tid; b < NWAVE; b += 256) {
        float4 p0 = *(const float4*)&pacc[(size_t)b * HH + c0];
        float4 p1 = *(const float4*)&pacc[(size_t)b * HH + c0 + 4];
        a[0] += p0.x; a[1] += p0.y; a[2] += p0.z; a[3] += p0.w;
        a[4] += p1.x; a[5] += p1.y; a[6] += p1.z; a[7] += p1.w;
    }
#pragma unroll
    for (int j = 0; j < 8; ++j)
#pragma unroll
        for (int off = 32; off; off >>= 1) a[j] += __shfl_xor(a[j], off, 64);
    if (lane == 0) {
#pragma unroll
        for (int j = 0; j < 8; ++j) red[wv * 8 + j] = a[j];
    }
    __syncthreads();
    if (tid < 8) {
        float s = red[tid] + red[8 + tid] + red[16 + tid] + red[24 + tid];
        out[c0 + tid] = s * inv;
    }
}

// ---------- score ----------
__global__ void score_k(const float* __restrict__ x, const float* __restrict__ sw,
                        const float* __restrict__ sb, float* __restrict__ out) {
    const int lane = threadIdx.x;   // 64
    float s = 0.f;
#pragma unroll
    for (int t = 0; t < 8; ++t) {
        int k = lane + 64 * t;
        s += x[k] * sw[k];
    }
#pragma unroll
    for (int off = 32; off; off >>= 1) s += __shfl_xor(s, off, 64);
    if (lane == 0) out[0] = s + sb[0];
}

// ---------- launcher ----------
extern "C" void kernel_launch(void* const* d_in, const int* in_sizes, int n_in,
                              void* d_out, int out_size, void* d_ws, size_t ws_size,
                              hipStream_t stream) {
    (void)in_sizes; (void)n_in; (void)out_size; (void)ws_size;
    const float* attn_mem = (const float*)d_in[0];
    const float* attn_wm  = (const float*)d_in[1];
    const float* attn_wq  = (const float*)d_in[2];
    const float* attn_v   = (const float*)d_in[3];
    const float* hop_wm   = (const float*)d_in[4];
    const float* hop_wq   = (const float*)d_in[5];
    const float* hop_v    = (const float*)d_in[6];
    const float* init_i   = (const float*)d_in[7];
    const float* init_h   = (const float*)d_in[8];
    const float* init_c   = (const float*)d_in[9];
    const float* w_ih     = (const float*)d_in[10];
    const float* w_hh     = (const float*)d_in[11];
    const float* b_ih     = (const float*)d_in[12];
    const float* b_hh     = (const float*)d_in[13];
    const float* score_w  = (const float*)d_in[14];
    const float* score_b  = (const float*)d_in[15];
    const int*   mask     = (const int*)d_in[16];
    float* dout = (float*)d_out;

    size_t off = 0;
    char* base = (char*)d_ws;
    auto carve = [&](size_t bytes) -> char* {
        char* p = base + off;
        off += (bytes + 255) & ~(size_t)255;
        return p;
    };
    ushort_t* Abf  = (ushort_t*)carve((size_t)NN * DD * 2);
    ushort_t* WT0  = (ushort_t*)carve((size_t)DD * HH * 2);
    ushort_t* WT1  = (ushort_t*)carve((size_t)DD * HH * 2);
    ushort_t* afeat = (ushort_t*)carve((size_t)NN * HH * 2);
    ushort_t* hfeat = (ushort_t*)carve((size_t)NN * HH * 2);
    float* pacc  = (float*)carve((size_t)NWAVE * HH * 4);
    float* pl    = (float*)carve((size_t)NWAVE * 4);
    float* gates = (float*)carve(4 * HH * 4);
    float* hbuf  = (float*)carve(HH * 4);
    float* cb0   = (float*)carve(HH * 4);
    float* cb1   = (float*)carve(HH * 4);
    float* qbuf  = (float*)carve(HH * 4);
    float* qwbuf = (float*)carve(HH * 4);
    float* xbuf  = (float*)carve(DD * 4);

    conv_bf16<<<(NN * DD / 8) / 256, 256, 0, stream>>>(attn_mem, Abf);
    conv_wt<<<dim3(128, 2), 256, 0, stream>>>(attn_wm, hop_wm, WT0, WT1);
    gemm_mfma<<<4096, 256, 0, stream>>>(Abf, WT0, WT1,
        (__hip_bfloat16*)afeat, (__hip_bfloat16*)hfeat);

    for (int s = 0; s < NSTEP; ++s) {
        const float* x   = s ? xbuf : init_i;
        const float* hin = s ? hbuf : init_h;
        const float* cin = s == 0 ? init_c : (s & 1 ? cb0 : cb1);
        float* cout      = (s & 1) ? cb1 : cb0;
        lstm_gates<<<512, 256, 0, stream>>>(x, hin, w_ih, w_hh, b_ih, b_hh, gates);
        lstm_tail<<<8, 512, 0, stream>>>(gates, cin, cout, hbuf, hop_wq, qwbuf);
        attn_partial<true><<<ABLOCKS, 256, 0, stream>>>(hfeat, nullptr, qwbuf, hop_v, mask, pl, pacc);
        attn_combine<<<64, 256, 0, stream>>>(pl, pacc, qbuf);
        vecmat512<<<8, 512, 0, stream>>>(qbuf, attn_wq, qwbuf);
        attn_partial<false><<<ABLOCKS, 256, 0, stream>>>(afeat, Abf, qwbuf, attn_v, mask, pl, pacc);
        attn_combine<<<64, 256, 0, stream>>>(pl, pacc, xbuf);
        score_k<<<1, 64, 0, stream>>>(xbuf, score_w, score_b, dout + s);
    }
}

// Round 8
// 500.964 us; speedup vs baseline: 2.7217x; 1.0018x over previous
//
#include <hip/hip_runtime.h>
#include <hip/hip_bf16.h>
#include <hip/hip_cooperative_groups.h>

namespace cg = cooperative_groups;

#define NN 65536
#define DD 512
#define HH 512
#define NSTEP 4
#define NEG_INFF -100000000.0f

#define RPW 16                 // rows per wave in attention phases
#define NWAVE 4096             // 4096 waves x 16 rows = 65536
#define ABLOCKS 1024           // fallback attn grid (256-thread blocks)
#define MEGA_BLOCKS 512        // cooperative grid (512-thread blocks)

typedef unsigned short ushort_t;
typedef __attribute__((ext_vector_type(8))) short bf16x8;
typedef __attribute__((ext_vector_type(4))) float f32x4;

// ---------- helpers ----------
__device__ __forceinline__ float bflo(unsigned u) {
    union { unsigned i; float f; } v; v.i = u << 16; return v.f;
}
__device__ __forceinline__ float bfhi(unsigned u) {
    union { unsigned i; float f; } v; v.i = u & 0xffff0000u; return v.f;
}
__device__ __forceinline__ float fast_tanh(float x) {
    float e = __expf(2.0f * x);
    return 1.0f - 2.0f * __builtin_amdgcn_rcpf(e + 1.0f);
}

#define GL2LDS(g, l) __builtin_amdgcn_global_load_lds( \
    (const __attribute__((address_space(1))) unsigned int*)(g), \
    (__attribute__((address_space(3))) unsigned int*)(l), 16, 0, 0)

// ---------- f32 -> bf16 convert (attn_mem) ----------
__global__ __launch_bounds__(256)
void conv_bf16(const float* __restrict__ in, ushort_t* __restrict__ out) {
    const int i = blockIdx.x * 256 + threadIdx.x;
    const size_t base = (size_t)i * 8;
    float4 a = *(const float4*)&in[base];
    float4 b = *(const float4*)&in[base + 4];
    union { __hip_bfloat16 h[8]; uint4 u; } t;
    t.h[0] = __float2bfloat16(a.x); t.h[1] = __float2bfloat16(a.y);
    t.h[2] = __float2bfloat16(a.z); t.h[3] = __float2bfloat16(a.w);
    t.h[4] = __float2bfloat16(b.x); t.h[5] = __float2bfloat16(b.y);
    t.h[6] = __float2bfloat16(b.z); t.h[7] = __float2bfloat16(b.w);
    *(uint4*)&out[base] = t.u;
}

// ---------- weight transpose + convert: WT[n][k] = bf16(W[k][n]) ----------
__global__ __launch_bounds__(256)
void conv_wt(const float* __restrict__ W0, const float* __restrict__ W1,
             ushort_t* __restrict__ T0, ushort_t* __restrict__ T1) {
    const float* W = blockIdx.y ? W1 : W0;
    ushort_t* T = blockIdx.y ? T1 : T0;
    const int n = blockIdx.x * 4 + (threadIdx.x >> 6);
    const int k0 = (threadIdx.x & 63) * 8;
    union { __hip_bfloat16 h[8]; uint4 u; } t;
#pragma unroll
    for (int i = 0; i < 8; ++i)
        t.h[i] = __float2bfloat16(W[(size_t)(k0 + i) * HH + n]);
    *(uint4*)&T[(size_t)n * DD + k0] = t.u;
}

// ---------- MFMA GEMM: XCD-locality grid + 2-phase LDS double-buffer ----------
#define TM 128
#define TK 32
#define NT (DD / TK)   // 16 K-steps
__global__ __launch_bounds__(256)
void gemm_mfma(const ushort_t* __restrict__ A,
               const ushort_t* __restrict__ WT0, const ushort_t* __restrict__ WT1,
               __hip_bfloat16* __restrict__ C0, __hip_bfloat16* __restrict__ C1) {
    __shared__ ushort_t As[2][TM * TK];
    __shared__ ushort_t Bs[2][TM * TK];
    const int L = blockIdx.x;
    const int xcd = L & 7;
    const int slot = L >> 3;
    const int mt = xcd * 64 + (slot >> 3);
    const int my = slot & 7;
    const ushort_t* WT = (my < 4) ? WT0 : WT1;
    __hip_bfloat16* Cp = (my < 4) ? C0 : C1;
    const int bn = (my & 3) * TM;
    const int bm = mt * TM;
    const int tid = threadIdx.x;
    const int lane = tid & 63;
    const int wid = tid >> 6;
    const int wr = (wid >> 1) * 64;
    const int wc = (wid & 1) * 64;
    const int l15 = lane & 15;
    const int srow = lane >> 2;
    const int ske = (((lane & 3) ^ ((lane >> 3) & 3)) * 8);
    const int koff = (((lane >> 4) ^ ((l15 >> 1) & 3)) << 3);

    const ushort_t* Abase = A + (size_t)bm * DD;
    const ushort_t* Bbase = WT + (size_t)bn * DD;

    auto stage = [&](int b, int k0) {
#pragma unroll
        for (int u = 0; u < 2; ++u) {
            const int g = u * 4 + wid;
            const int row = g * 16 + srow;
            GL2LDS(Abase + (size_t)row * DD + k0 + ske, &As[b][g * 512]);
            GL2LDS(Bbase + (size_t)row * DD + k0 + ske, &Bs[b][g * 512]);
        }
    };

    const f32x4 zero = {0.f, 0.f, 0.f, 0.f};
    f32x4 acc[4][4];
#pragma unroll
    for (int m = 0; m < 4; ++m)
#pragma unroll
        for (int n = 0; n < 4; ++n) acc[m][n] = zero;

    stage(0, 0);
    stage(1, TK);
    __builtin_amdgcn_sched_barrier(0);

    for (int t = 0; t < NT; ++t) {
        const int cur = t & 1;
        if (t + 1 < NT) asm volatile("s_waitcnt vmcnt(4)" ::: "memory");
        else            asm volatile("s_waitcnt vmcnt(0)" ::: "memory");
        __builtin_amdgcn_sched_barrier(0);
        __builtin_amdgcn_s_barrier();
        __builtin_amdgcn_sched_barrier(0);

        bf16x8 af[4], bfr[4];
#pragma unroll
        for (int m = 0; m < 4; ++m)
            af[m] = *(const bf16x8*)(&As[cur][(wr + m * 16 + l15) * TK + koff]);
#pragma unroll
        for (int n = 0; n < 4; ++n)
            bfr[n] = *(const bf16x8*)(&Bs[cur][(wc + n * 16 + l15) * TK + koff]);
#pragma unroll
        for (int m = 0; m < 4; ++m)
#pragma unroll
            for (int n = 0; n < 4; ++n)
                acc[m][n] = __builtin_amdgcn_mfma_f32_16x16x32_bf16(af[m], bfr[n], acc[m][n], 0, 0, 0);

        asm volatile("s_waitcnt lgkmcnt(0)" ::: "memory");
        __builtin_amdgcn_sched_barrier(0);
        __builtin_amdgcn_s_barrier();
        __builtin_amdgcn_sched_barrier(0);
        if (t + 2 < NT) stage(cur, (t + 2) * TK);
        __builtin_amdgcn_sched_barrier(0);
    }

    const int r0 = (lane >> 4) * 4;
#pragma unroll
    for (int m = 0; m < 4; ++m) {
#pragma unroll
        for (int n = 0; n < 4; ++n) {
            const f32x4 vv = acc[m][n];
            const size_t cb = (size_t)(bm + wr + m * 16 + r0) * HH + bn + wc + n * 16 + l15;
#pragma unroll
            for (int r = 0; r < 4; ++r)
                Cp[cb + (size_t)r * HH] = __float2bfloat16(vv[r]);
        }
    }
}

// ---------- attention streaming body (identical math to r6 attn_partial) ----------
template<bool HOP>
__device__ __forceinline__
void attn_body(const ushort_t* __restrict__ feat, const ushort_t* __restrict__ mem,
               const float* __restrict__ qw, const float* __restrict__ v,
               const int* __restrict__ mask,
               float* __restrict__ pl, float* __restrict__ pacc,
               int wave, int lane) {
    float qv[8], vv[8];
    {
        float4 q0 = *(const float4*)&qw[lane * 8];
        float4 q1 = *(const float4*)&qw[lane * 8 + 4];
        qv[0] = q0.x; qv[1] = q0.y; qv[2] = q0.z; qv[3] = q0.w;
        qv[4] = q1.x; qv[5] = q1.y; qv[6] = q1.z; qv[7] = q1.w;
        float4 v0 = *(const float4*)&v[lane * 8];
        float4 v1 = *(const float4*)&v[lane * 8 + 4];
        vv[0] = v0.x; vv[1] = v0.y; vv[2] = v0.z; vv[3] = v0.w;
        vv[4] = v1.x; vv[5] = v1.y; vv[6] = v1.z; vv[7] = v1.w;
    }
    float C = 0.f;
#pragma unroll
    for (int j = 0; j < 8; ++j) C += fabsf(vv[j]);
#pragma unroll
    for (int o = 32; o; o >>= 1) C += __shfl_xor(C, o, 64);

    float lsum = 0.f;
    float acc[8];
#pragma unroll
    for (int j = 0; j < 8; ++j) acc[j] = 0.f;
    const int row0 = wave * RPW;

    uint4 fc = *(const uint4*)(feat + (size_t)row0 * HH + lane * 8);
    uint4 mc;
    if (!HOP) mc = *(const uint4*)(mem + (size_t)row0 * DD + lane * 8);
#pragma unroll 4
    for (int r = 0; r < RPW; ++r) {
        uint4 fn, mn;
        if (r + 1 < RPW) {
            fn = *(const uint4*)(feat + (size_t)(row0 + r + 1) * HH + lane * 8);
            if (!HOP) mn = *(const uint4*)(mem + (size_t)(row0 + r + 1) * DD + lane * 8);
        }
        float f[8];
        f[0] = bflo(fc.x); f[1] = bfhi(fc.x); f[2] = bflo(fc.y); f[3] = bfhi(fc.y);
        f[4] = bflo(fc.z); f[5] = bfhi(fc.z); f[6] = bflo(fc.w); f[7] = bfhi(fc.w);
        float mv[8];
        if (!HOP) {
            mv[0] = bflo(mc.x); mv[1] = bfhi(mc.x); mv[2] = bflo(mc.y); mv[3] = bfhi(mc.y);
            mv[4] = bflo(mc.z); mv[5] = bfhi(mc.z); mv[6] = bflo(mc.w); mv[7] = bfhi(mc.w);
        } else {
#pragma unroll
            for (int j = 0; j < 8; ++j) mv[j] = f[j];
        }
        float d = 0.f;
#pragma unroll
        for (int j = 0; j < 8; ++j) d += fast_tanh(f[j] + qv[j]) * vv[j];
#pragma unroll
        for (int o = 32; o; o >>= 1) d += __shfl_xor(d, o, 64);
        const float sc = d - C + (mask[row0 + r] ? 0.f : NEG_INFF);
        const float p = __expf(sc);
        lsum += p;
#pragma unroll
        for (int j = 0; j < 8; ++j) acc[j] += p * mv[j];
        fc = fn;
        if (!HOP) mc = mn;
    }
    const size_t base = (size_t)wave * HH + lane * 8;
    *(float4*)&pacc[base]     = make_float4(acc[0], acc[1], acc[2], acc[3]);
    *(float4*)&pacc[base + 4] = make_float4(acc[4], acc[5], acc[6], acc[7]);
    if (lane == 0) pl[wave] = lsum;
}

// ---------- combine body (block-size generic): out[c0..c0+7] ----------
__device__ __forceinline__
void combine_body(const float* __restrict__ pl, const float* __restrict__ pacc,
                  float* __restrict__ out, float* __restrict__ sh,
                  int c0, int tid, int nthr) {
    const int lane = tid & 63, wv = tid >> 6;
    const int nw = nthr >> 6;
    float lg = 0.f;
    for (int b = tid; b < NWAVE; b += nthr) lg += pl[b];
#pragma unroll
    for (int o = 32; o; o >>= 1) lg += __shfl_xor(lg, o, 64);
    if (lane == 0) sh[wv] = lg;
    __syncthreads();
    float lt = 0.f;
    for (int r = 0; r < nw; ++r) lt += sh[r];
    const float inv = 1.0f / lt;
    __syncthreads();
    float a[8];
#pragma unroll
    for (int j = 0; j < 8; ++j) a[j] = 0.f;
    for (int b = tid; b < NWAVE; b += nthr) {
        float4 p0 = *(const float4*)&pacc[(size_t)b * HH + c0];
        float4 p1 = *(const float4*)&pacc[(size_t)b * HH + c0 + 4];
        a[0] += p0.x; a[1] += p0.y; a[2] += p0.z; a[3] += p0.w;
        a[4] += p1.x; a[5] += p1.y; a[6] += p1.z; a[7] += p1.w;
    }
#pragma unroll
    for (int j = 0; j < 8; ++j)
#pragma unroll
        for (int o = 32; o; o >>= 1) a[j] += __shfl_xor(a[j], o, 64);
    if (lane == 0) {
#pragma unroll
        for (int j = 0; j < 8; ++j) sh[wv * 8 + j] = a[j];
    }
    __syncthreads();
    if (tid < 8) {
        float s2 = 0.f;
        for (int r = 0; r < nw; ++r) s2 += sh[r * 8 + tid];
        out[c0 + tid] = s2 * inv;
    }
}

// ---------- cooperative mega-kernel: whole 4-step loop ----------
// 512 blocks x 512 threads (8 waves) -> 4096 waves, RPW=16 (r6 geometry).
// launch_bounds(512,4): 4 waves/EU -> 2 blocks/CU -> needs 512 of ~1024 slots.
__global__ __launch_bounds__(512, 4)
void step_mega(const ushort_t* __restrict__ afeat, const ushort_t* __restrict__ hfeat,
               const ushort_t* __restrict__ Abf,
               const float* __restrict__ w_ih, const float* __restrict__ w_hh,
               const float* __restrict__ b_ih, const float* __restrict__ b_hh,
               const float* __restrict__ hop_wq, const float* __restrict__ attn_wq,
               const float* __restrict__ hop_v, const float* __restrict__ attn_v,
               const float* __restrict__ score_w, const float* __restrict__ score_b,
               const int* __restrict__ mask,
               const float* __restrict__ init_i, const float* __restrict__ init_h,
               const float* __restrict__ init_c,
               float* __restrict__ gates, float* __restrict__ hbuf,
               float* __restrict__ cb0, float* __restrict__ cb1,
               float* __restrict__ qbuf, float* __restrict__ qwbuf,
               float* __restrict__ xbuf,
               float* __restrict__ pl, float* __restrict__ pacc,
               float* __restrict__ dout) {
    cg::grid_group grid = cg::this_grid();
    __shared__ float sh[1024];
    const int tid = threadIdx.x;      // 0..511
    const int bid = blockIdx.x;       // 0..511
    const int lane = tid & 63;
    const int wv = tid >> 6;          // 0..7
    const int gwave = bid * 8 + wv;   // 0..4095

    for (int s = 0; s < NSTEP; ++s) {
        const float* x   = s ? xbuf : init_i;
        const float* hin = s ? hbuf : init_h;
        const float* cin = (s == 0) ? init_c : ((s & 1) ? cb0 : cb1);
        float* co        = (s & 1) ? cb1 : cb0;

        // --- L1: LSTM gates, one wave per gate row (waves 0..2047)
        if (gwave < 4 * HH) {
            const float* wi = w_ih + (size_t)gwave * DD;
            const float* wh = w_hh + (size_t)gwave * HH;
            float sum = 0.f;
#pragma unroll
            for (int t = 0; t < 8; ++t) {
                const int k = lane + 64 * t;
                sum += wi[k] * x[k] + wh[k] * hin[k];
            }
#pragma unroll
            for (int o = 32; o; o >>= 1) sum += __shfl_xor(sum, o, 64);
            if (lane == 0) gates[gwave] = sum + b_ih[gwave] + b_hh[gwave];
        }
        grid.sync();

        // --- L2: h,c update + qw_hop = h @ hop_wq (blocks 0..7; r6 lstm_tail body)
        if (bid < 8) {
            {
                const int j = tid;   // 0..511
                const float ig = gates[j], fg = gates[HH + j];
                const float gg = gates[2 * HH + j], og = gates[3 * HH + j];
                const float si = 1.f / (1.f + __expf(-ig));
                const float sf = 1.f / (1.f + __expf(-fg));
                const float so = 1.f / (1.f + __expf(-og));
                const float cn = sf * cin[j] + si * tanhf(gg);
                const float hn = so * tanhf(cn);
                sh[j] = hn;
                if (bid == 0) { co[j] = cn; hbuf[j] = hn; }
            }
            __syncthreads();
            const int col = bid * 64 + lane;
            float sum = 0.f;
            const int k0 = wv * 64;
#pragma unroll 4
            for (int k = k0; k < k0 + 64; ++k) sum += sh[k] * hop_wq[(size_t)k * HH + col];
            sh[512 + wv * 64 + lane] = sum;
            __syncthreads();
            if (wv == 0) {
                float t2 = 0.f;
#pragma unroll
                for (int r = 0; r < 8; ++r) t2 += sh[512 + r * 64 + lane];
                qwbuf[col] = t2;
            }
        }
        grid.sync();

        // --- A1: hop attention partials (all blocks)
        attn_body<true>(hfeat, nullptr, qwbuf, hop_v, mask, pl, pacc, gwave, lane);
        grid.sync();

        // --- C1: combine -> qbuf (blocks 0..63)
        if (bid < 64) combine_body(pl, pacc, qbuf, sh, bid * 8, tid, 512);
        grid.sync();

        // --- V: qw2 = qbuf @ attn_wq (blocks 0..7)
        if (bid < 8) {
            sh[tid] = qbuf[tid];
            __syncthreads();
            const int col = bid * 64 + lane;
            float sum = 0.f;
            const int k0 = wv * 64;
#pragma unroll 4
            for (int k = k0; k < k0 + 64; ++k) sum += sh[k] * attn_wq[(size_t)k * HH + col];
            sh[512 + wv * 64 + lane] = sum;
            __syncthreads();
            if (wv == 0) {
                float t2 = 0.f;
#pragma unroll
                for (int r = 0; r < 8; ++r) t2 += sh[512 + r * 64 + lane];
                qwbuf[col] = t2;
            }
        }
        grid.sync();

        // --- A2: final attention partials (values = bf16 attn_mem)
        attn_body<false>(afeat, Abf, qwbuf, attn_v, mask, pl, pacc, gwave, lane);
        grid.sync();

        // --- C2: combine -> xbuf (blocks 0..63)
        if (bid < 64) combine_body(pl, pacc, xbuf, sh, bid * 8, tid, 512);
        grid.sync();

        // --- S: score (block 0, wave 0); next L1 only touches gates (disjoint)
        if (bid == 0 && wv == 0) {
            float sum = 0.f;
#pragma unroll
            for (int t = 0; t < 8; ++t) {
                const int k = lane + 64 * t;
                sum += xbuf[k] * score_w[k];
            }
#pragma unroll
            for (int o = 32; o; o >>= 1) sum += __shfl_xor(sum, o, 64);
            if (lane == 0) dout[s] = sum + score_b[0];
        }
    }
}

// ---------- fallback kernels (r6-proven path) ----------
__global__ __launch_bounds__(256)
void lstm_gates(const float* __restrict__ x, const float* __restrict__ h,
                const float* __restrict__ w_ih, const float* __restrict__ w_hh,
                const float* __restrict__ b_ih, const float* __restrict__ b_hh,
                float* __restrict__ gates) {
    const int wave = (blockIdx.x * 256 + threadIdx.x) >> 6;
    const int lane = threadIdx.x & 63;
    const float* wi = w_ih + (size_t)wave * DD;
    const float* wh = w_hh + (size_t)wave * HH;
    float s = 0.f;
#pragma unroll
    for (int t = 0; t < 8; ++t) {
        int k = lane + 64 * t;
        s += wi[k] * x[k] + wh[k] * h[k];
    }
#pragma unroll
    for (int off = 32; off; off >>= 1) s += __shfl_xor(s, off, 64);
    if (lane == 0) gates[wave] = s + b_ih[wave] + b_hh[wave];
}

__global__ __launch_bounds__(512)
void lstm_tail(const float* __restrict__ gates, const float* __restrict__ cin,
               float* __restrict__ cout, float* __restrict__ hout,
               const float* __restrict__ Wq, float* __restrict__ qwout) {
    __shared__ float hs[HH];
    __shared__ float red[8][64];
    const int j = threadIdx.x;
    {
        float ig = gates[j], fg = gates[HH + j], gg = gates[2 * HH + j], og = gates[3 * HH + j];
        float si = 1.f / (1.f + __expf(-ig));
        float sf = 1.f / (1.f + __expf(-fg));
        float so = 1.f / (1.f + __expf(-og));
        float cn = sf * cin[j] + si * tanhf(gg);
        float hn = so * tanhf(cn);
        hs[j] = hn;
        if (blockIdx.x == 0) { cout[j] = cn; hout[j] = hn; }
    }
    __syncthreads();
    const int lane = threadIdx.x & 63, wv = threadIdx.x >> 6;
    const int col = blockIdx.x * 64 + lane;
    float s = 0.f;
    const int k0 = wv * 64;
#pragma unroll 4
    for (int k = k0; k < k0 + 64; ++k) s += hs[k] * Wq[(size_t)k * HH + col];
    red[wv][lane] = s;
    __syncthreads();
    if (wv == 0) {
        float t = 0.f;
#pragma unroll
        for (int r = 0; r < 8; ++r) t += red[r][lane];
        qwout[col] = t;
    }
}

__global__ __launch_bounds__(512)
void vecmat512(const float* __restrict__ q, const float* __restrict__ W,
               float* __restrict__ out) {
    __shared__ float red[8][64];
    const int lane = threadIdx.x & 63, wv = threadIdx.x >> 6;
    const int j = blockIdx.x * 64 + lane;
    float s = 0.f;
    const int k0 = wv * 64;
#pragma unroll 4
    for (int k = k0; k < k0 + 64; ++k) s += q[k] * W[(size_t)k * HH + j];
    red[wv][lane] = s;
    __syncthreads();
    if (wv == 0) {
        float t = 0.f;
#pragma unroll
        for (int r = 0; r < 8; ++r) t += red[r][lane];
        out[j] = t;
    }
}

template<bool HOP>
__global__ __launch_bounds__(256)
void attn_partial_k(const ushort_t* __restrict__ feat, const ushort_t* __restrict__ mem,
                    const float* __restrict__ qw, const float* __restrict__ v,
                    const int* __restrict__ mask,
                    float* __restrict__ pl, float* __restrict__ pacc) {
    attn_body<HOP>(feat, mem, qw, v, mask, pl, pacc,
                   blockIdx.x * 4 + (threadIdx.x >> 6), threadIdx.x & 63);
}

__global__ __launch_bounds__(256)
void attn_combine_k(const float* __restrict__ pl, const float* __restrict__ pacc,
                    float* __restrict__ out) {
    __shared__ float sh[64];
    combine_body(pl, pacc, out, sh, blockIdx.x * 8, threadIdx.x, 256);
}

__global__ void score_k(const float* __restrict__ x, const float* __restrict__ sw,
                        const float* __restrict__ sb, float* __restrict__ out) {
    const int lane = threadIdx.x;   // 64
    float s = 0.f;
#pragma unroll
    for (int t = 0; t < 8; ++t) {
        int k = lane + 64 * t;
        s += x[k] * sw[k];
    }
#pragma unroll
    for (int off = 32; off; off >>= 1) s += __shfl_xor(s, off, 64);
    if (lane == 0) out[0] = s + sb[0];
}

// ---------- launcher ----------
extern "C" void kernel_launch(void* const* d_in, const int* in_sizes, int n_in,
                              void* d_out, int out_size, void* d_ws, size_t ws_size,
                              hipStream_t stream) {
    (void)in_sizes; (void)n_in; (void)out_size; (void)ws_size;
    const float* attn_mem = (const float*)d_in[0];
    const float* attn_wm  = (const float*)d_in[1];
    const float* attn_wq  = (const float*)d_in[2];
    const float* attn_v   = (const float*)d_in[3];
    const float* hop_wm   = (const float*)d_in[4];
    const float* hop_wq   = (const float*)d_in[5];
    const float* hop_v    = (const float*)d_in[6];
    const float* init_i   = (const float*)d_in[7];
    const float* init_h   = (const float*)d_in[8];
    const float* init_c   = (const float*)d_in[9];
    const float* w_ih     = (const float*)d_in[10];
    const float* w_hh     = (const float*)d_in[11];
    const float* b_ih     = (const float*)d_in[12];
    const float* b_hh     = (const float*)d_in[13];
    const float* score_w  = (const float*)d_in[14];
    const float* score_b  = (const float*)d_in[15];
    const int*   mask     = (const int*)d_in[16];
    float* dout = (float*)d_out;

    size_t off = 0;
    char* base = (char*)d_ws;
    auto carve = [&](size_t bytes) -> char* {
        char* p = base + off;
        off += (bytes + 255) & ~(size_t)255;
        return p;
    };
    ushort_t* Abf   = (ushort_t*)carve((size_t)NN * DD * 2);
    ushort_t* WT0   = (ushort_t*)carve((size_t)DD * HH * 2);
    ushort_t* WT1   = (ushort_t*)carve((size_t)DD * HH * 2);
    ushort_t* afeat = (ushort_t*)carve((size_t)NN * HH * 2);
    ushort_t* hfeat = (ushort_t*)carve((size_t)NN * HH * 2);
    float* pacc  = (float*)carve((size_t)NWAVE * HH * 4);
    float* pl    = (float*)carve((size_t)NWAVE * 4);
    float* gates = (float*)carve(4 * HH * 4);
    float* hbuf  = (float*)carve(HH * 4);
    float* cb0   = (float*)carve(HH * 4);
    float* cb1   = (float*)carve(HH * 4);
    float* qbuf  = (float*)carve(HH * 4);
    float* qwbuf = (float*)carve(HH * 4);
    float* xbuf  = (float*)carve(DD * 4);

    conv_bf16<<<(NN * DD / 8) / 256, 256, 0, stream>>>(attn_mem, Abf);
    conv_wt<<<dim3(128, 2), 256, 0, stream>>>(attn_wm, hop_wm, WT0, WT1);
    gemm_mfma<<<4096, 256, 0, stream>>>(Abf, WT0, WT1,
        (__hip_bfloat16*)afeat, (__hip_bfloat16*)hfeat);

    // decide coop vs fallback via host-side occupancy query (deterministic,
    // graph-capture-safe: no allocation, no sync, no stream ops)
    int dev = 0;
    (void)hipGetDevice(&dev);
    int numCU = 0;
    (void)hipDeviceGetAttribute(&numCU, hipDeviceAttributeMultiprocessorCount, dev);
    int maxBlk = 0;
    (void)hipOccupancyMaxActiveBlocksPerMultiprocessor(&maxBlk, (const void*)step_mega, 512, 0);
    bool coop_ok = (maxBlk > 0) && ((long)maxBlk * (long)numCU >= MEGA_BLOCKS);

    if (coop_ok) {
        const ushort_t* k_afeat = afeat;
        const ushort_t* k_hfeat = hfeat;
        const ushort_t* k_Abf   = Abf;
        void* args[] = {
            (void*)&k_afeat, (void*)&k_hfeat, (void*)&k_Abf,
            (void*)&w_ih, (void*)&w_hh, (void*)&b_ih, (void*)&b_hh,
            (void*)&hop_wq, (void*)&attn_wq, (void*)&hop_v, (void*)&attn_v,
            (void*)&score_w, (void*)&score_b, (void*)&mask,
            (void*)&init_i, (void*)&init_h, (void*)&init_c,
            (void*)&gates, (void*)&hbuf, (void*)&cb0, (void*)&cb1,
            (void*)&qbuf, (void*)&qwbuf, (void*)&xbuf,
            (void*)&pl, (void*)&pacc, (void*)&dout
        };
        coop_ok = (hipLaunchCooperativeKernel((void*)step_mega, dim3(MEGA_BLOCKS),
                                              dim3(512), args, 0, stream) == hipSuccess);
    }
    if (!coop_ok) {
        // r6-proven multi-kernel fallback
        for (int s = 0; s < NSTEP; ++s) {
            const float* x   = s ? xbuf : init_i;
            const float* hin = s ? hbuf : init_h;
            const float* cin = s == 0 ? init_c : (s & 1 ? cb0 : cb1);
            float* cout      = (s & 1) ? cb1 : cb0;
            lstm_gates<<<512, 256, 0, stream>>>(x, hin, w_ih, w_hh, b_ih, b_hh, gates);
            lstm_tail<<<8, 512, 0, stream>>>(gates, cin, cout, hbuf, hop_wq, qwbuf);
            attn_partial_k<true><<<ABLOCKS, 256, 0, stream>>>(hfeat, nullptr, qwbuf, hop_v, mask, pl, pacc);
            attn_combine_k<<<64, 256, 0, stream>>>(pl, pacc, qbuf);
            vecmat512<<<8, 512, 0, stream>>>(qbuf, attn_wq, qwbuf);
            attn_partial_k<false><<<ABLOCKS, 256, 0, stream>>>(afeat, Abf, qwbuf, attn_v, mask, pl, pacc);
            attn_combine_k<<<64, 256, 0, stream>>>(pl, pacc, xbuf);
            score_k<<<1, 64, 0, stream>>>(xbuf, score_w, score_b, dout + s);
        }
    }
}